// Round 1
// baseline (236.180 us; speedup 1.0000x reference)
//
#include <hip/hip_runtime.h>

// Encoder layer, MI355X. Pipeline:
//  styles -> dcoef -> lnorm -> convert weights (bf16; out-proj pre-scaled per b)
//  -> QKV GEMM (bf16 MFMA, epilogue scales, also writes V^T) -> flash attn -> out GEMM.
// ws usage ~70.2 MB.

typedef unsigned short u16;
typedef __attribute__((ext_vector_type(8))) short s16x8;   // 8 bf16 (4 VGPRs)
typedef __attribute__((ext_vector_type(4))) float f32x4;
typedef __attribute__((ext_vector_type(4))) unsigned short u16x4;

#define SCALE_QK 0.17677669529663687f   // 1/sqrt(32)
#define WGAIN_C  0.044194173824159216f  // 1/sqrt(512)

__device__ __forceinline__ u16 f2bf(float f) {
  union { float f; unsigned u; } v; v.f = f;
  return (u16)((v.u + 0x7FFFu + ((v.u >> 16) & 1u)) >> 16);
}

__device__ __forceinline__ void gl_lds16(const u16* g, u16* l) {
  __builtin_amdgcn_global_load_lds(
      (const __attribute__((address_space(1))) unsigned int*)g,
      (__attribute__((address_space(3))) unsigned int*)l, 16, 0, 0);
}

// ---------------- styles = w @ (affine_w.T * WGAIN) + affine_b ----------------
// one wave per output element (4 waves/block), 8192 outputs
__global__ __launch_bounds__(256) void styles_k(const float* __restrict__ w,
    const float* __restrict__ aw, const float* __restrict__ ab,
    float* __restrict__ styles) {
  int lane = threadIdx.x & 63;
  int gid = blockIdx.x * 4 + (threadIdx.x >> 6);   // 0..8191
  int b = gid >> 11;
  int col = gid & 2047;
  const float* awr = aw + (size_t)col * 512 + lane * 8;
  const float* wr  = w + b * 512 + lane * 8;
  float4 a0 = *(const float4*)awr;
  float4 a1 = *(const float4*)(awr + 4);
  float4 w0 = *(const float4*)wr;
  float4 w1 = *(const float4*)(wr + 4);
  float acc = a0.x*w0.x + a0.y*w0.y + a0.z*w0.z + a0.w*w0.w
            + a1.x*w1.x + a1.y*w1.y + a1.z*w1.z + a1.w*w1.w;
  #pragma unroll
  for (int m = 1; m < 64; m <<= 1) acc += __shfl_xor(acc, m);
  if (lane == 0) styles[gid] = acc * WGAIN_C + ab[col];
}

// ---------------- dcoef: rsqrt(sum_j (W[i,j]*s[b,j])^2 + 1e-8) ----------------
// mats 0..2 (q,k,v) use s1; 3..4 (w,u) use s2; mat 2 additionally *= s2[b,i]
__global__ __launch_bounds__(256) void dcoef_k(const float* __restrict__ qw,
    const float* __restrict__ kw, const float* __restrict__ vw,
    const float* __restrict__ ww, const float* __restrict__ uw,
    const float* __restrict__ styles,
    float* __restrict__ scl_qkv, float* __restrict__ scl_ou) {
  int lane = threadIdx.x & 63;
  int gid = blockIdx.x * 4 + (threadIdx.x >> 6);   // 0..20479
  int mat = gid >> 12;
  int rem = gid & 4095;
  int b = rem >> 10;
  int i = rem & 1023;
  const float* W = (mat == 0 ? qw : mat == 1 ? kw : mat == 2 ? vw : mat == 3 ? ww : uw)
                   + (size_t)i * 1024 + lane * 16;
  const float* s = styles + b * 2048 + (mat >= 3 ? 1024 : 0) + lane * 16;
  float acc = 0.f;
  #pragma unroll
  for (int j = 0; j < 16; j += 4) {
    float4 wv = *(const float4*)(W + j);
    float4 sv = *(const float4*)(s + j);
    float m0 = wv.x*sv.x, m1 = wv.y*sv.y, m2 = wv.z*sv.z, m3 = wv.w*sv.w;
    acc += m0*m0 + m1*m1 + m2*m2 + m3*m3;
  }
  #pragma unroll
  for (int m = 1; m < 64; m <<= 1) acc += __shfl_xor(acc, m);
  if (lane == 0) {
    float d = rsqrtf(acc + 1e-8f);
    if (mat == 2) d *= styles[b * 2048 + 1024 + i];   // fold *s2 into v scale
    if (mat < 3) scl_qkv[mat * 4096 + b * 1024 + i] = d;
    else         scl_ou[(mat - 3) * 4096 + b * 1024 + i] = d;
  }
}

// ---------------- x = LN(x * s1) -> bf16 ----------------
__global__ __launch_bounds__(256) void lnorm_k(const float* __restrict__ x,
    const float* __restrict__ styles, u16* __restrict__ xn) {
  int row = blockIdx.x;            // 0..4095
  int b = row >> 10;
  int t = threadIdx.x;
  const float* xr = x + (size_t)row * 1024 + t * 4;
  const float* sr = styles + b * 2048 + t * 4;
  float4 xv = *(const float4*)xr;
  float4 sv = *(const float4*)sr;
  float y0 = xv.x*sv.x, y1 = xv.y*sv.y, y2 = xv.z*sv.z, y3 = xv.w*sv.w;
  float sum = y0 + y1 + y2 + y3;
  float ssq = y0*y0 + y1*y1 + y2*y2 + y3*y3;
  #pragma unroll
  for (int m = 1; m < 64; m <<= 1) { sum += __shfl_xor(sum, m); ssq += __shfl_xor(ssq, m); }
  __shared__ float red[8];
  int wave = t >> 6;
  if ((t & 63) == 0) { red[wave] = sum; red[4 + wave] = ssq; }
  __syncthreads();
  sum = red[0] + red[1] + red[2] + red[3];
  ssq = red[4] + red[5] + red[6] + red[7];
  float mu = sum * (1.f / 1024.f);
  float var = ssq * (1.f / 1024.f) - mu * mu;
  float rs = rsqrtf(var + 1e-5f);
  u16x4 o = { f2bf((y0-mu)*rs), f2bf((y1-mu)*rs), f2bf((y2-mu)*rs), f2bf((y3-mu)*rs) };
  *(u16x4*)(xn + (size_t)row * 1024 + t * 4) = o;
}

// ---------------- convert q/k/v weights f32 -> bf16 (row-major [n][k] = B^T) ----------------
__global__ __launch_bounds__(256) void convq_k(const float* __restrict__ qw,
    const float* __restrict__ kw, const float* __restrict__ vw, u16* __restrict__ dst) {
  int t = blockIdx.x * 256 + threadIdx.x;  // *8 elems, total 3M
  int e0 = t * 8;
  int mat = e0 >> 20;
  int off = e0 & 1048575;
  const float* src = (mat == 0 ? qw : mat == 1 ? kw : vw) + off;
  float4 a = *(const float4*)src;
  float4 c = *(const float4*)(src + 4);
  u16x4 lo = { f2bf(a.x), f2bf(a.y), f2bf(a.z), f2bf(a.w) };
  u16x4 hi = { f2bf(c.x), f2bf(c.y), f2bf(c.z), f2bf(c.w) };
  *(u16x4*)(dst + e0) = lo;
  *(u16x4*)(dst + e0 + 4) = hi;
}

// ---------------- out-proj weights: dst[b][n][k(0..2047)] = (k<1024?Ww*wd : Wu*ud) ----------------
__global__ __launch_bounds__(256) void convou_k(const float* __restrict__ ww,
    const float* __restrict__ uw, const float* __restrict__ scl_ou, u16* __restrict__ dst) {
  int t = blockIdx.x * 256 + threadIdx.x;  // *8 elems, total 8M
  int e0 = t * 8;
  int b = e0 >> 21;
  int rem = e0 & 2097151;
  int n = rem >> 11;
  int k0 = rem & 2047;
  int half = k0 >> 10;
  const float* src = half ? uw + (size_t)n * 1024 + (k0 - 1024)
                          : ww + (size_t)n * 1024 + k0;
  float sc = scl_ou[half * 4096 + b * 1024 + n];
  float4 a = *(const float4*)src;
  float4 c = *(const float4*)(src + 4);
  u16x4 lo = { f2bf(a.x*sc), f2bf(a.y*sc), f2bf(a.z*sc), f2bf(a.w*sc) };
  u16x4 hi = { f2bf(c.x*sc), f2bf(c.y*sc), f2bf(c.z*sc), f2bf(c.w*sc) };
  *(u16x4*)(dst + e0) = lo;
  *(u16x4*)(dst + e0 + 4) = hi;
}

// ---------------- QKV GEMM: C = xn @ W^T, 128x128 tile, BK=32, 4 waves 2x2 ----------------
// N=3072 (q|k|v). Epilogue: *scale[b,n]; v also written transposed (Vt[b][n][s]).
__global__ __launch_bounds__(256) void gemm_qkv_k(const u16* __restrict__ A,
    const u16* __restrict__ Bw, const float* __restrict__ scl_qkv,
    u16* __restrict__ qout, u16* __restrict__ kout, u16* __restrict__ vov,
    u16* __restrict__ vtout) {
  __shared__ u16 Asm[128][32];
  __shared__ u16 Bsm[128][32];
  int tid = threadIdx.x;
  int lane = tid & 63;
  int qi = lane & 15, g = lane >> 4;
  int wave = tid >> 6;
  int wm = wave >> 1, wn = wave & 1;
  int m0 = blockIdx.x * 128;
  int n0 = blockIdx.y * 128;
  f32x4 acc[4][4] = {};
  const u16* ag = A  + (size_t)(m0 + (tid >> 2)) * 1024 + (tid & 3) * 8;
  const u16* bg = Bw + (size_t)(n0 + (tid >> 2)) * 1024 + (tid & 3) * 8;
  u16* as0 = &Asm[0][0] + tid * 8;
  u16* bs0 = &Bsm[0][0] + tid * 8;
  for (int k0 = 0; k0 < 1024; k0 += 32) {
    gl_lds16(ag + k0, as0);
    gl_lds16(ag + 64 * 1024 + k0, as0 + 2048);
    gl_lds16(bg + k0, bs0);
    gl_lds16(bg + 64 * 1024 + k0, bs0 + 2048);
    __syncthreads();
    s16x8 af[4], bf[4];
    #pragma unroll
    for (int i = 0; i < 4; i++) af[i] = *(const s16x8*)&Asm[wm * 64 + i * 16 + qi][g * 8];
    #pragma unroll
    for (int j = 0; j < 4; j++) bf[j] = *(const s16x8*)&Bsm[wn * 64 + j * 16 + qi][g * 8];
    #pragma unroll
    for (int i = 0; i < 4; i++)
      #pragma unroll
      for (int j = 0; j < 4; j++)
        acc[i][j] = __builtin_amdgcn_mfma_f32_16x16x32_bf16(af[i], bf[j], acc[i][j], 0, 0, 0);
    __syncthreads();
  }
  int which = n0 >> 10;           // uniform per block (128 | 1024)
  int nl0 = n0 & 1023;
  int b = m0 >> 10;
  const float* scl = scl_qkv + which * 4096 + b * 1024;
  u16* outp; int ostride;
  if (which == 0)      { outp = qout; ostride = 1024; }
  else if (which == 1) { outp = kout; ostride = 1024; }
  else                 { outp = vov;  ostride = 2048; }   // v cols of ov buffer
  #pragma unroll
  for (int i = 0; i < 4; i++) {
    int mrow = m0 + wm * 64 + i * 16 + g * 4;
    #pragma unroll
    for (int j = 0; j < 4; j++) {
      int nl = nl0 + wn * 64 + j * 16 + qi;
      float s = scl[nl];
      u16 b0 = f2bf(acc[i][j][0] * s), b1 = f2bf(acc[i][j][1] * s);
      u16 b2 = f2bf(acc[i][j][2] * s), b3 = f2bf(acc[i][j][3] * s);
      outp[(size_t)(mrow + 0) * ostride + nl] = b0;
      outp[(size_t)(mrow + 1) * ostride + nl] = b1;
      outp[(size_t)(mrow + 2) * ostride + nl] = b2;
      outp[(size_t)(mrow + 3) * ostride + nl] = b3;
      if (which == 2) {
        u16x4 pk = { b0, b1, b2, b3 };
        *(u16x4*)(vtout + (size_t)(b * 1024 + nl) * 1024 + (mrow - b * 1024)) = pk;
      }
    }
  }
}

// ---------------- flash attention: 1 wave / (b,h,16 q rows); swapped QK^T ----------------
__global__ __launch_bounds__(64) void attn_k(const u16* __restrict__ q,
    const u16* __restrict__ k, const u16* __restrict__ vt, u16* __restrict__ oout) {
  __shared__ u16 P[16][32];
  int lane = threadIdx.x;
  int qi = lane & 15, g = lane >> 4;
  int qt = blockIdx.x & 63;
  int hb = blockIdx.x >> 6;
  int b = hb >> 5, h = hb & 31;
  int q0 = qt * 16;
  // Q b-frag: Q[q0+qi][h*32 + g*8 + j]
  s16x8 qf = *(const s16x8*)(q + (size_t)((b << 10) + q0 + qi) * 1024 + h * 32 + g * 8);
  const u16* kp = k  + (size_t)(b << 10) * 1024 + h * 32 + g * 8;
  const u16* vp = vt + (size_t)((b << 10) + h * 32) * 1024 + g * 8;
  float m = -1e30f, lsum = 0.f;
  f32x4 o0 = {0.f, 0.f, 0.f, 0.f}, o1 = {0.f, 0.f, 0.f, 0.f};
  f32x4 zero = {0.f, 0.f, 0.f, 0.f};
  for (int kt = 0; kt < 1024; kt += 32) {
    s16x8 kf0 = *(const s16x8*)(kp + (size_t)(kt + qi) * 1024);
    s16x8 kf1 = *(const s16x8*)(kp + (size_t)(kt + 16 + qi) * 1024);
    // S^T[kn][q]: per lane, q = qi, kn = c*16 + g*4 + r
    f32x4 s0 = __builtin_amdgcn_mfma_f32_16x16x32_bf16(kf0, qf, zero, 0, 0, 0);
    f32x4 s1 = __builtin_amdgcn_mfma_f32_16x16x32_bf16(kf1, qf, zero, 0, 0, 0);
    float c0[4], c1[4];
    float cm = -1e30f;
    #pragma unroll
    for (int r = 0; r < 4; r++) {
      c0[r] = s0[r] * SCALE_QK; c1[r] = s1[r] * SCALE_QK;
      cm = fmaxf(cm, fmaxf(c0[r], c1[r]));
    }
    cm = fmaxf(cm, __shfl_xor(cm, 16));
    cm = fmaxf(cm, __shfl_xor(cm, 32));
    float nm = fmaxf(m, cm);
    float f = __expf(m - nm);
    float p0[4], p1[4], ps = 0.f;
    #pragma unroll
    for (int r = 0; r < 4; r++) {
      p0[r] = __expf(c0[r] - nm); p1[r] = __expf(c1[r] - nm);
      ps += p0[r] + p1[r];
    }
    ps += __shfl_xor(ps, 16);
    ps += __shfl_xor(ps, 32);
    lsum = lsum * f + ps;
    m = nm;
    #pragma unroll
    for (int r = 0; r < 4; r++) { o0[r] *= f; o1[r] *= f; }
    #pragma unroll
    for (int r = 0; r < 4; r++) {
      P[qi][g * 4 + r]      = f2bf(p0[r]);
      P[qi][16 + g * 4 + r] = f2bf(p1[r]);
    }
    __syncthreads();
    // PV: O^T[d][q] += V^T[d][kn] * P^T[kn][q]
    s16x8 pf = *(const s16x8*)&P[qi][g * 8];
    s16x8 va = *(const s16x8*)(vp + (size_t)qi * 1024 + kt);
    s16x8 vc = *(const s16x8*)(vp + (size_t)(16 + qi) * 1024 + kt);
    o0 = __builtin_amdgcn_mfma_f32_16x16x32_bf16(va, pf, o0, 0, 0, 0);
    o1 = __builtin_amdgcn_mfma_f32_16x16x32_bf16(vc, pf, o1, 0, 0, 0);
    __syncthreads();
  }
  float inv = 1.f / lsum;
  u16x4 w0 = { f2bf(o0[0]*inv), f2bf(o0[1]*inv), f2bf(o0[2]*inv), f2bf(o0[3]*inv) };
  u16x4 w1 = { f2bf(o1[0]*inv), f2bf(o1[1]*inv), f2bf(o1[2]*inv), f2bf(o1[3]*inv) };
  u16* orow = oout + (size_t)((b << 10) + q0 + qi) * 2048 + h * 32;  // o cols of ov
  *(u16x4*)(orow + g * 4) = w0;
  *(u16x4*)(orow + 16 + g * 4) = w1;
}

// ---------------- out GEMM: C = ov @ Bsc[b]^T (K=2048), 128x64 tile, 4 waves 4x1 ----------------
__global__ __launch_bounds__(256) void gemm_out_k(const u16* __restrict__ A,
    const u16* __restrict__ Bw, const float* __restrict__ noi,
    const float* __restrict__ nst, const float* __restrict__ bias,
    float* __restrict__ out) {
  __shared__ u16 Asm[128][32];
  __shared__ u16 Bsm[64][32];
  int tid = threadIdx.x;
  int lane = tid & 63;
  int qi = lane & 15, g = lane >> 4;
  int wave = tid >> 6;            // row band
  int m0 = blockIdx.x * 128;
  int n0 = blockIdx.y * 64;
  int b = m0 >> 10;
  f32x4 acc[2][4] = {};
  const u16* ag = A + (size_t)(m0 + (tid >> 2)) * 2048 + (tid & 3) * 8;
  const u16* bg = Bw + (size_t)b * 2048 * 1024 + (size_t)(n0 + (tid >> 2)) * 2048 + (tid & 3) * 8;
  u16* as0 = &Asm[0][0] + tid * 8;
  u16* bs0 = &Bsm[0][0] + tid * 8;
  for (int k0 = 0; k0 < 2048; k0 += 32) {
    gl_lds16(ag + k0, as0);
    gl_lds16(ag + 64 * 2048 + k0, as0 + 2048);
    gl_lds16(bg + k0, bs0);
    __syncthreads();
    s16x8 af[2], bf[4];
    #pragma unroll
    for (int i = 0; i < 2; i++) af[i] = *(const s16x8*)&Asm[wave * 32 + i * 16 + qi][g * 8];
    #pragma unroll
    for (int j = 0; j < 4; j++) bf[j] = *(const s16x8*)&Bsm[j * 16 + qi][g * 8];
    #pragma unroll
    for (int i = 0; i < 2; i++)
      #pragma unroll
      for (int j = 0; j < 4; j++)
        acc[i][j] = __builtin_amdgcn_mfma_f32_16x16x32_bf16(af[i], bf[j], acc[i][j], 0, 0, 0);
    __syncthreads();
  }
  float ns = nst[0];
  #pragma unroll
  for (int i = 0; i < 2; i++) {
    #pragma unroll
    for (int j = 0; j < 4; j++) {
      int n = n0 + j * 16 + qi;
      float bv = bias[n];
      #pragma unroll
      for (int r = 0; r < 4; r++) {
        int mrow = m0 + wave * 32 + i * 16 + g * 4 + r;
        float v = acc[i][j][r] + noi[mrow] * ns + bv;
        v = (v >= 0.f) ? v : 0.2f * v;
        v = fminf(fmaxf(v, -256.f), 256.f);
        out[(size_t)mrow * 1024 + n] = v;
      }
    }
  }
}

extern "C" void kernel_launch(void* const* d_in, const int* in_sizes, int n_in,
                              void* d_out, int out_size, void* d_ws, size_t ws_size,
                              hipStream_t stream) {
  const float* x    = (const float*)d_in[0];
  const float* w    = (const float*)d_in[1];
  const float* aw   = (const float*)d_in[2];
  const float* ab   = (const float*)d_in[3];
  const float* qw   = (const float*)d_in[4];
  const float* kw   = (const float*)d_in[5];
  const float* vw   = (const float*)d_in[6];
  const float* wwp  = (const float*)d_in[7];
  const float* uwp  = (const float*)d_in[8];
  const float* bias = (const float*)d_in[9];
  const float* nst  = (const float*)d_in[10];
  const float* noi  = (const float*)d_in[11];
  float* out = (float*)d_out;

  char* ws = (char*)d_ws;
  float* styles  = (float*)ws;  ws += 8192 * 4;           // [4][2048]
  float* scl_qkv = (float*)ws;  ws += 3 * 4096 * 4;       // [3][4][1024]
  float* scl_ou  = (float*)ws;  ws += 2 * 4096 * 4;       // [2][4][1024]
  u16* xn   = (u16*)ws;         ws += (size_t)4194304 * 2; // [4096][1024]
  u16* wbq  = (u16*)ws;         ws += (size_t)3145728 * 2; // [3][1024][1024]
  u16* wbou = (u16*)ws;         ws += (size_t)8388608 * 2; // [4][1024][2048] prescaled
  u16* qb   = (u16*)ws;         ws += (size_t)4194304 * 2; // [4096][1024]
  u16* kb   = (u16*)ws;         ws += (size_t)4194304 * 2; // [4096][1024]
  u16* vt   = (u16*)ws;         ws += (size_t)4194304 * 2; // [4][1024 hd][1024 s]
  u16* ov   = (u16*)ws;         ws += (size_t)8388608 * 2; // [4096][2048] = [o | v]

  styles_k<<<dim3(2048), dim3(256), 0, stream>>>(w, aw, ab, styles);
  dcoef_k<<<dim3(5120), dim3(256), 0, stream>>>(qw, kw, vw, wwp, uwp, styles, scl_qkv, scl_ou);
  lnorm_k<<<dim3(4096), dim3(256), 0, stream>>>(x, styles, xn);
  convq_k<<<dim3(1536), dim3(256), 0, stream>>>(qw, kw, vw, wbq);
  convou_k<<<dim3(4096), dim3(256), 0, stream>>>(wwp, uwp, scl_ou, wbou);
  gemm_qkv_k<<<dim3(32, 24), dim3(256), 0, stream>>>(xn, wbq, scl_qkv, qb, kb, ov + 1024, vt);
  attn_k<<<dim3(8192), dim3(64), 0, stream>>>(qb, kb, vt, ov);
  gemm_out_k<<<dim3(32, 16), dim3(256), 0, stream>>>(ov, wbou, noi, nst, bias, out);
}

// Round 2
// 159.051 us; speedup vs baseline: 1.4849x; 1.4849x over previous
//
#include <hip/hip_runtime.h>

// Encoder layer, MI355X. Pipeline:
//  styles -> dcoef -> lnorm -> convert weights (bf16; out-proj pre-scaled per b)
//  -> QKV GEMM (bf16 MFMA, epilogue scales; Q pre-scaled by SCALE*log2e, writes V^T)
//  -> flash attn (4-wave blocks, KVBLK=64, LDS-staged K/V dbuf) -> out GEMM.

typedef unsigned short u16;
typedef __attribute__((ext_vector_type(8))) short s16x8;   // 8 bf16 (4 VGPRs)
typedef __attribute__((ext_vector_type(4))) float f32x4;
typedef __attribute__((ext_vector_type(4))) unsigned short u16x4;
typedef __attribute__((ext_vector_type(2))) unsigned int u32x2;

#define WGAIN_C  0.044194173824159216f  // 1/sqrt(512)
// 1/sqrt(32) * log2(e) : folded into Q so attention scores are log2-domain
#define SCALE_L2E (0.17677669529663687f * 1.4426950408889634f)

__device__ __forceinline__ u16 f2bf(float f) {
  union { float f; unsigned u; } v; v.f = f;
  return (u16)((v.u + 0x7FFFu + ((v.u >> 16) & 1u)) >> 16);
}

__device__ __forceinline__ unsigned cvtpk(float lo, float hi) {
  unsigned r;
  asm("v_cvt_pk_bf16_f32 %0, %1, %2" : "=v"(r) : "v"(lo), "v"(hi));
  return r;
}

__device__ __forceinline__ void gl_lds16(const u16* g, u16* l) {
  __builtin_amdgcn_global_load_lds(
      (const __attribute__((address_space(1))) unsigned int*)g,
      (__attribute__((address_space(3))) unsigned int*)l, 16, 0, 0);
}

// ---------------- styles = w @ (affine_w.T * WGAIN) + affine_b ----------------
__global__ __launch_bounds__(256) void styles_k(const float* __restrict__ w,
    const float* __restrict__ aw, const float* __restrict__ ab,
    float* __restrict__ styles) {
  int lane = threadIdx.x & 63;
  int gid = blockIdx.x * 4 + (threadIdx.x >> 6);   // 0..8191
  int b = gid >> 11;
  int col = gid & 2047;
  const float* awr = aw + (size_t)col * 512 + lane * 8;
  const float* wr  = w + b * 512 + lane * 8;
  float4 a0 = *(const float4*)awr;
  float4 a1 = *(const float4*)(awr + 4);
  float4 w0 = *(const float4*)wr;
  float4 w1 = *(const float4*)(wr + 4);
  float acc = a0.x*w0.x + a0.y*w0.y + a0.z*w0.z + a0.w*w0.w
            + a1.x*w1.x + a1.y*w1.y + a1.z*w1.z + a1.w*w1.w;
  #pragma unroll
  for (int m = 1; m < 64; m <<= 1) acc += __shfl_xor(acc, m);
  if (lane == 0) styles[gid] = acc * WGAIN_C + ab[col];
}

// ---------------- dcoef: rsqrt(sum_j (W[i,j]*s[b,j])^2 + 1e-8) ----------------
__global__ __launch_bounds__(256) void dcoef_k(const float* __restrict__ qw,
    const float* __restrict__ kw, const float* __restrict__ vw,
    const float* __restrict__ ww, const float* __restrict__ uw,
    const float* __restrict__ styles,
    float* __restrict__ scl_qkv, float* __restrict__ scl_ou) {
  int lane = threadIdx.x & 63;
  int gid = blockIdx.x * 4 + (threadIdx.x >> 6);   // 0..20479
  int mat = gid >> 12;
  int rem = gid & 4095;
  int b = rem >> 10;
  int i = rem & 1023;
  const float* W = (mat == 0 ? qw : mat == 1 ? kw : mat == 2 ? vw : mat == 3 ? ww : uw)
                   + (size_t)i * 1024 + lane * 16;
  const float* s = styles + b * 2048 + (mat >= 3 ? 1024 : 0) + lane * 16;
  float acc = 0.f;
  #pragma unroll
  for (int j = 0; j < 16; j += 4) {
    float4 wv = *(const float4*)(W + j);
    float4 sv = *(const float4*)(s + j);
    float m0 = wv.x*sv.x, m1 = wv.y*sv.y, m2 = wv.z*sv.z, m3 = wv.w*sv.w;
    acc += m0*m0 + m1*m1 + m2*m2 + m3*m3;
  }
  #pragma unroll
  for (int m = 1; m < 64; m <<= 1) acc += __shfl_xor(acc, m);
  if (lane == 0) {
    float d = rsqrtf(acc + 1e-8f);
    if (mat == 2) d *= styles[b * 2048 + 1024 + i];   // fold *s2 into v scale
    if (mat < 3) scl_qkv[mat * 4096 + b * 1024 + i] = d;
    else         scl_ou[(mat - 3) * 4096 + b * 1024 + i] = d;
  }
}

// ---------------- x = LN(x * s1) -> bf16 ----------------
__global__ __launch_bounds__(256) void lnorm_k(const float* __restrict__ x,
    const float* __restrict__ styles, u16* __restrict__ xn) {
  int row = blockIdx.x;            // 0..4095
  int b = row >> 10;
  int t = threadIdx.x;
  const float* xr = x + (size_t)row * 1024 + t * 4;
  const float* sr = styles + b * 2048 + t * 4;
  float4 xv = *(const float4*)xr;
  float4 sv = *(const float4*)sr;
  float y0 = xv.x*sv.x, y1 = xv.y*sv.y, y2 = xv.z*sv.z, y3 = xv.w*sv.w;
  float sum = y0 + y1 + y2 + y3;
  float ssq = y0*y0 + y1*y1 + y2*y2 + y3*y3;
  #pragma unroll
  for (int m = 1; m < 64; m <<= 1) { sum += __shfl_xor(sum, m); ssq += __shfl_xor(ssq, m); }
  __shared__ float red[8];
  int wave = t >> 6;
  if ((t & 63) == 0) { red[wave] = sum; red[4 + wave] = ssq; }
  __syncthreads();
  sum = red[0] + red[1] + red[2] + red[3];
  ssq = red[4] + red[5] + red[6] + red[7];
  float mu = sum * (1.f / 1024.f);
  float var = ssq * (1.f / 1024.f) - mu * mu;
  float rs = rsqrtf(var + 1e-5f);
  u16x4 o = { f2bf((y0-mu)*rs), f2bf((y1-mu)*rs), f2bf((y2-mu)*rs), f2bf((y3-mu)*rs) };
  *(u16x4*)(xn + (size_t)row * 1024 + t * 4) = o;
}

// ---------------- convert q/k/v weights f32 -> bf16 ----------------
__global__ __launch_bounds__(256) void convq_k(const float* __restrict__ qw,
    const float* __restrict__ kw, const float* __restrict__ vw, u16* __restrict__ dst) {
  int t = blockIdx.x * 256 + threadIdx.x;
  int e0 = t * 8;
  int mat = e0 >> 20;
  int off = e0 & 1048575;
  const float* src = (mat == 0 ? qw : mat == 1 ? kw : vw) + off;
  float4 a = *(const float4*)src;
  float4 c = *(const float4*)(src + 4);
  u16x4 lo = { f2bf(a.x), f2bf(a.y), f2bf(a.z), f2bf(a.w) };
  u16x4 hi = { f2bf(c.x), f2bf(c.y), f2bf(c.z), f2bf(c.w) };
  *(u16x4*)(dst + e0) = lo;
  *(u16x4*)(dst + e0 + 4) = hi;
}

// ---------------- out-proj weights: prescaled per batch ----------------
__global__ __launch_bounds__(256) void convou_k(const float* __restrict__ ww,
    const float* __restrict__ uw, const float* __restrict__ scl_ou, u16* __restrict__ dst) {
  int t = blockIdx.x * 256 + threadIdx.x;
  int e0 = t * 8;
  int b = e0 >> 21;
  int rem = e0 & 2097151;
  int n = rem >> 11;
  int k0 = rem & 2047;
  int half = k0 >> 10;
  const float* src = half ? uw + (size_t)n * 1024 + (k0 - 1024)
                          : ww + (size_t)n * 1024 + k0;
  float sc = scl_ou[half * 4096 + b * 1024 + n];
  float4 a = *(const float4*)src;
  float4 c = *(const float4*)(src + 4);
  u16x4 lo = { f2bf(a.x*sc), f2bf(a.y*sc), f2bf(a.z*sc), f2bf(a.w*sc) };
  u16x4 hi = { f2bf(c.x*sc), f2bf(c.y*sc), f2bf(c.z*sc), f2bf(c.w*sc) };
  *(u16x4*)(dst + e0) = lo;
  *(u16x4*)(dst + e0 + 4) = hi;
}

// ---------------- QKV GEMM: C = xn @ W^T, 128x128 tile, BK=32 ----------------
__global__ __launch_bounds__(256) void gemm_qkv_k(const u16* __restrict__ A,
    const u16* __restrict__ Bw, const float* __restrict__ scl_qkv,
    u16* __restrict__ qout, u16* __restrict__ kout, u16* __restrict__ vov,
    u16* __restrict__ vtout) {
  __shared__ u16 Asm[128][32];
  __shared__ u16 Bsm[128][32];
  int tid = threadIdx.x;
  int lane = tid & 63;
  int qi = lane & 15, g = lane >> 4;
  int wave = tid >> 6;
  int wm = wave >> 1, wn = wave & 1;
  int m0 = blockIdx.x * 128;
  int n0 = blockIdx.y * 128;
  f32x4 acc[4][4] = {};
  const u16* ag = A  + (size_t)(m0 + (tid >> 2)) * 1024 + (tid & 3) * 8;
  const u16* bg = Bw + (size_t)(n0 + (tid >> 2)) * 1024 + (tid & 3) * 8;
  u16* as0 = &Asm[0][0] + tid * 8;
  u16* bs0 = &Bsm[0][0] + tid * 8;
  for (int k0 = 0; k0 < 1024; k0 += 32) {
    gl_lds16(ag + k0, as0);
    gl_lds16(ag + 64 * 1024 + k0, as0 + 2048);
    gl_lds16(bg + k0, bs0);
    gl_lds16(bg + 64 * 1024 + k0, bs0 + 2048);
    __syncthreads();
    s16x8 af[4], bf[4];
    #pragma unroll
    for (int i = 0; i < 4; i++) af[i] = *(const s16x8*)&Asm[wm * 64 + i * 16 + qi][g * 8];
    #pragma unroll
    for (int j = 0; j < 4; j++) bf[j] = *(const s16x8*)&Bsm[wn * 64 + j * 16 + qi][g * 8];
    #pragma unroll
    for (int i = 0; i < 4; i++)
      #pragma unroll
      for (int j = 0; j < 4; j++)
        acc[i][j] = __builtin_amdgcn_mfma_f32_16x16x32_bf16(af[i], bf[j], acc[i][j], 0, 0, 0);
    __syncthreads();
  }
  int which = n0 >> 10;           // uniform per block
  int nl0 = n0 & 1023;
  int b = m0 >> 10;
  const float* scl = scl_qkv + which * 4096 + b * 1024;
  u16* outp; int ostride;
  if (which == 0)      { outp = qout; ostride = 1024; }
  else if (which == 1) { outp = kout; ostride = 1024; }
  else                 { outp = vov;  ostride = 2048; }   // v cols of ov buffer
  #pragma unroll
  for (int i = 0; i < 4; i++) {
    int mrow = m0 + wm * 64 + i * 16 + g * 4;
    #pragma unroll
    for (int j = 0; j < 4; j++) {
      int nl = nl0 + wn * 64 + j * 16 + qi;
      float s = scl[nl];
      if (which == 0) s *= SCALE_L2E;   // fold softmax scale + log2e into Q
      u16 b0 = f2bf(acc[i][j][0] * s), b1 = f2bf(acc[i][j][1] * s);
      u16 b2 = f2bf(acc[i][j][2] * s), b3 = f2bf(acc[i][j][3] * s);
      outp[(size_t)(mrow + 0) * ostride + nl] = b0;
      outp[(size_t)(mrow + 1) * ostride + nl] = b1;
      outp[(size_t)(mrow + 2) * ostride + nl] = b2;
      outp[(size_t)(mrow + 3) * ostride + nl] = b3;
      if (which == 2) {
        u16x4 pk = { b0, b1, b2, b3 };
        *(u16x4*)(vtout + (size_t)(b * 1024 + nl) * 1024 + (mrow - b * 1024)) = pk;
      }
    }
  }
}

// ---------------- flash attention ----------------
// 4 waves / block, 64 q rows (wave w: rows q0+w*16..+15), KVBLK=64,
// K[64][32] + V^T[32][64] LDS double-buffered via global_load_lds.
// Scores arrive pre-scaled by SCALE*log2e (folded into Q) -> exp2 domain.
__global__ __launch_bounds__(256) void attn_k(const u16* __restrict__ q,
    const u16* __restrict__ k, const u16* __restrict__ vt, u16* __restrict__ oout) {
  __shared__ u16 Kl[2][2048];   // [key][d] linear, 4KB each
  __shared__ u16 Vl[2][2048];   // [d][s], col-swizzled by (row&1), 4KB each
  __shared__ u16 Pl[4][1024];   // per-wave P [16 q][64 kn], col-swizzled by (qi&3)
  int tid = threadIdx.x;
  int lane = tid & 63;
  int w = tid >> 6;
  int qi = lane & 15, g = lane >> 4;
  int qblk = blockIdx.x & 15;
  int bh = blockIdx.x >> 4;
  int b = bh >> 5, h = bh & 31;
  int q0 = qblk * 64;
  s16x8 qf = *(const s16x8*)(q + (size_t)((b << 10) + q0 + w * 16 + qi) * 1024 + h * 32 + g * 8);
  const u16* kbase = k + (size_t)(b << 10) * 1024 + h * 32;
  const u16* vbase = vt + (size_t)((b << 10) + h * 32) * 1024;
  int kr = tid >> 2, kc = tid & 3;                 // K stage: key row, 16B chunk
  int vr = tid >> 3, vc = tid & 7;                 // V stage: d row, 16B chunk
  int vcs = vc ^ ((vr & 1) << 2);                  // pre-swizzled global chunk
  u16* Pw = &Pl[w][0];
  int swq = (qi & 3) << 4;                         // P swizzle (elem units)
  int swv = (qi & 1) << 5;                         // V swizzle (elem units)
  float mrun = -1e30f, lsum = 0.f;
  f32x4 o0 = {0.f,0.f,0.f,0.f}, o1 = {0.f,0.f,0.f,0.f};
  const f32x4 zero = {0.f,0.f,0.f,0.f};

  gl_lds16(kbase + (size_t)kr * 1024 + kc * 8, &Kl[0][0] + tid * 8);
  gl_lds16(vbase + (size_t)vr * 1024 + vcs * 8, &Vl[0][0] + tid * 8);
  __syncthreads();

  for (int it = 0; it < 16; ++it) {
    int nb = it & 1;
    if (it < 15) {
      int ktn = (it + 1) * 64;
      gl_lds16(kbase + (size_t)(ktn + kr) * 1024 + kc * 8, &Kl[nb ^ 1][0] + tid * 8);
      gl_lds16(vbase + (size_t)vr * 1024 + ktn + vcs * 8, &Vl[nb ^ 1][0] + tid * 8);
    }
    // QK^T (swapped): sa[kg][r] = S^T[kn = kg*16 + g*4 + r][q = qi], log2-domain
    f32x4 sa[4];
    #pragma unroll
    for (int kg = 0; kg < 4; kg++) {
      s16x8 kf = *(const s16x8*)(&Kl[nb][0] + (kg * 16 + qi) * 32 + g * 8);
      sa[kg] = __builtin_amdgcn_mfma_f32_16x16x32_bf16(kf, qf, zero, 0, 0, 0);
    }
    float cm = -1e30f;
    #pragma unroll
    for (int kg = 0; kg < 4; kg++)
      #pragma unroll
      for (int r = 0; r < 4; r++) cm = fmaxf(cm, sa[kg][r]);
    cm = fmaxf(cm, __shfl_xor(cm, 16));
    cm = fmaxf(cm, __shfl_xor(cm, 32));
    float nm = fmaxf(mrun, cm);
    float f = __builtin_amdgcn_exp2f(mrun - nm);
    float ps = 0.f;
    #pragma unroll
    for (int kg = 0; kg < 4; kg++) {
      float p0 = __builtin_amdgcn_exp2f(sa[kg][0] - nm);
      float p1 = __builtin_amdgcn_exp2f(sa[kg][1] - nm);
      float p2 = __builtin_amdgcn_exp2f(sa[kg][2] - nm);
      float p3 = __builtin_amdgcn_exp2f(sa[kg][3] - nm);
      ps += (p0 + p1) + (p2 + p3);
      u32x2 pkv = { cvtpk(p0, p1), cvtpk(p2, p3) };
      *(u32x2*)(Pw + qi * 64 + ((kg * 16 + g * 4) ^ swq)) = pkv;
    }
    ps += __shfl_xor(ps, 16);
    ps += __shfl_xor(ps, 32);
    lsum = lsum * f + ps;
    mrun = nm;
    #pragma unroll
    for (int r = 0; r < 4; r++) { o0[r] *= f; o1[r] *= f; }
    // PV: O^T[d][q] += V^T[d][kn] * P^T[kn][q]
    #pragma unroll
    for (int half = 0; half < 2; half++) {
      s16x8 pf  = *(const s16x8*)(Pw + qi * 64 + ((half * 32 + g * 8) ^ swq));
      s16x8 va0 = *(const s16x8*)(&Vl[nb][0] + qi * 64 + ((half * 32 + g * 8) ^ swv));
      s16x8 va1 = *(const s16x8*)(&Vl[nb][0] + (16 + qi) * 64 + ((half * 32 + g * 8) ^ swv));
      o0 = __builtin_amdgcn_mfma_f32_16x16x32_bf16(va0, pf, o0, 0, 0, 0);
      o1 = __builtin_amdgcn_mfma_f32_16x16x32_bf16(va1, pf, o1, 0, 0, 0);
    }
    __syncthreads();
  }
  float inv = 1.f / lsum;
  u16* orow = oout + (size_t)((b << 10) + q0 + w * 16 + qi) * 2048 + h * 32;
  u16x4 w0 = { f2bf(o0[0]*inv), f2bf(o0[1]*inv), f2bf(o0[2]*inv), f2bf(o0[3]*inv) };
  u16x4 w1 = { f2bf(o1[0]*inv), f2bf(o1[1]*inv), f2bf(o1[2]*inv), f2bf(o1[3]*inv) };
  *(u16x4*)(orow + g * 4) = w0;
  *(u16x4*)(orow + 16 + g * 4) = w1;
}

// ---------------- out GEMM: C = ov @ Bsc[b]^T (K=2048), 128x64 tile ----------------
__global__ __launch_bounds__(256) void gemm_out_k(const u16* __restrict__ A,
    const u16* __restrict__ Bw, const float* __restrict__ noi,
    const float* __restrict__ nst, const float* __restrict__ bias,
    float* __restrict__ out) {
  __shared__ u16 Asm[128][32];
  __shared__ u16 Bsm[64][32];
  int tid = threadIdx.x;
  int lane = tid & 63;
  int qi = lane & 15, g = lane >> 4;
  int wave = tid >> 6;            // row band
  int m0 = blockIdx.x * 128;
  int n0 = blockIdx.y * 64;
  int b = m0 >> 10;
  f32x4 acc[2][4] = {};
  const u16* ag = A + (size_t)(m0 + (tid >> 2)) * 2048 + (tid & 3) * 8;
  const u16* bg = Bw + (size_t)b * 2048 * 1024 + (size_t)(n0 + (tid >> 2)) * 2048 + (tid & 3) * 8;
  u16* as0 = &Asm[0][0] + tid * 8;
  u16* bs0 = &Bsm[0][0] + tid * 8;
  for (int k0 = 0; k0 < 2048; k0 += 32) {
    gl_lds16(ag + k0, as0);
    gl_lds16(ag + 64 * 2048 + k0, as0 + 2048);
    gl_lds16(bg + k0, bs0);
    __syncthreads();
    s16x8 af[2], bf[4];
    #pragma unroll
    for (int i = 0; i < 2; i++) af[i] = *(const s16x8*)&Asm[wave * 32 + i * 16 + qi][g * 8];
    #pragma unroll
    for (int j = 0; j < 4; j++) bf[j] = *(const s16x8*)&Bsm[j * 16 + qi][g * 8];
    #pragma unroll
    for (int i = 0; i < 2; i++)
      #pragma unroll
      for (int j = 0; j < 4; j++)
        acc[i][j] = __builtin_amdgcn_mfma_f32_16x16x32_bf16(af[i], bf[j], acc[i][j], 0, 0, 0);
    __syncthreads();
  }
  float ns = nst[0];
  #pragma unroll
  for (int i = 0; i < 2; i++) {
    #pragma unroll
    for (int j = 0; j < 4; j++) {
      int n = n0 + j * 16 + qi;
      float bv = bias[n];
      #pragma unroll
      for (int r = 0; r < 4; r++) {
        int mrow = m0 + wave * 32 + i * 16 + g * 4 + r;
        float v = acc[i][j][r] + noi[mrow] * ns + bv;
        v = (v >= 0.f) ? v : 0.2f * v;
        v = fminf(fmaxf(v, -256.f), 256.f);
        out[(size_t)mrow * 1024 + n] = v;
      }
    }
  }
}

extern "C" void kernel_launch(void* const* d_in, const int* in_sizes, int n_in,
                              void* d_out, int out_size, void* d_ws, size_t ws_size,
                              hipStream_t stream) {
  const float* x    = (const float*)d_in[0];
  const float* w    = (const float*)d_in[1];
  const float* aw   = (const float*)d_in[2];
  const float* ab   = (const float*)d_in[3];
  const float* qw   = (const float*)d_in[4];
  const float* kw   = (const float*)d_in[5];
  const float* vw   = (const float*)d_in[6];
  const float* wwp  = (const float*)d_in[7];
  const float* uwp  = (const float*)d_in[8];
  const float* bias = (const float*)d_in[9];
  const float* nst  = (const float*)d_in[10];
  const float* noi  = (const float*)d_in[11];
  float* out = (float*)d_out;

  char* ws = (char*)d_ws;
  float* styles  = (float*)ws;  ws += 8192 * 4;           // [4][2048]
  float* scl_qkv = (float*)ws;  ws += 3 * 4096 * 4;       // [3][4][1024]
  float* scl_ou  = (float*)ws;  ws += 2 * 4096 * 4;       // [2][4][1024]
  u16* xn   = (u16*)ws;         ws += (size_t)4194304 * 2; // [4096][1024]
  u16* wbq  = (u16*)ws;         ws += (size_t)3145728 * 2; // [3][1024][1024]
  u16* wbou = (u16*)ws;         ws += (size_t)8388608 * 2; // [4][1024][2048] prescaled
  u16* qb   = (u16*)ws;         ws += (size_t)4194304 * 2; // [4096][1024]
  u16* kb   = (u16*)ws;         ws += (size_t)4194304 * 2; // [4096][1024]
  u16* vt   = (u16*)ws;         ws += (size_t)4194304 * 2; // [4][1024 hd][1024 s]
  u16* ov   = (u16*)ws;         ws += (size_t)8388608 * 2; // [4096][2048] = [o | v]

  styles_k<<<dim3(2048), dim3(256), 0, stream>>>(w, aw, ab, styles);
  dcoef_k<<<dim3(5120), dim3(256), 0, stream>>>(qw, kw, vw, wwp, uwp, styles, scl_qkv, scl_ou);
  lnorm_k<<<dim3(4096), dim3(256), 0, stream>>>(x, styles, xn);
  convq_k<<<dim3(1536), dim3(256), 0, stream>>>(qw, kw, vw, wbq);
  convou_k<<<dim3(4096), dim3(256), 0, stream>>>(wwp, uwp, scl_ou, wbou);
  gemm_qkv_k<<<dim3(32, 24), dim3(256), 0, stream>>>(xn, wbq, scl_qkv, qb, kb, ov + 1024, vt);
  attn_k<<<dim3(2048), dim3(256), 0, stream>>>(qb, kb, vt, ov);
  gemm_out_k<<<dim3(32, 16), dim3(256), 0, stream>>>(ov, wbou, noi, nst, bias, out);
}

// Round 3
// 150.129 us; speedup vs baseline: 1.5732x; 1.0594x over previous
//
#include <hip/hip_runtime.h>

// Encoder layer, MI355X. Pipeline:
//  styles -> dcoef -> lnorm -> convert weights (bf16; out-proj pre-scaled per b)
//  -> QKV GEMM (bf16 MFMA, epilogue scales; Q pre-scaled by SCALE*log2e, writes V^T)
//  -> flash attn (4-wave blocks, KVBLK=64, conflict-free LDS swizzles, XCD-chunked)
//  -> out GEMM.

typedef unsigned short u16;
typedef __attribute__((ext_vector_type(8))) short s16x8;   // 8 bf16 (4 VGPRs)
typedef __attribute__((ext_vector_type(4))) float f32x4;
typedef __attribute__((ext_vector_type(4))) unsigned short u16x4;
typedef __attribute__((ext_vector_type(2))) unsigned int u32x2;

#define WGAIN_C  0.044194173824159216f  // 1/sqrt(512)
// 1/sqrt(32) * log2(e) : folded into Q so attention scores are log2-domain
#define SCALE_L2E (0.17677669529663687f * 1.4426950408889634f)

__device__ __forceinline__ u16 f2bf(float f) {
  union { float f; unsigned u; } v; v.f = f;
  return (u16)((v.u + 0x7FFFu + ((v.u >> 16) & 1u)) >> 16);
}

__device__ __forceinline__ unsigned cvtpk(float lo, float hi) {
  unsigned r;
  asm("v_cvt_pk_bf16_f32 %0, %1, %2" : "=v"(r) : "v"(lo), "v"(hi));
  return r;
}

__device__ __forceinline__ void gl_lds16(const u16* g, u16* l) {
  __builtin_amdgcn_global_load_lds(
      (const __attribute__((address_space(1))) unsigned int*)g,
      (__attribute__((address_space(3))) unsigned int*)l, 16, 0, 0);
}

// ---------------- styles = w @ (affine_w.T * WGAIN) + affine_b ----------------
// one wave per column, all 4 batches (aw row read once)
__global__ __launch_bounds__(256) void styles_k(const float* __restrict__ w,
    const float* __restrict__ aw, const float* __restrict__ ab,
    float* __restrict__ styles) {
  int lane = threadIdx.x & 63;
  int col = blockIdx.x * 4 + (threadIdx.x >> 6);   // 0..2047
  const float* awr = aw + (size_t)col * 512 + lane * 8;
  float4 a0 = *(const float4*)awr;
  float4 a1 = *(const float4*)(awr + 4);
  float d[4];
  #pragma unroll
  for (int b = 0; b < 4; b++) {
    const float* wr = w + b * 512 + lane * 8;
    float4 w0 = *(const float4*)wr;
    float4 w1 = *(const float4*)(wr + 4);
    d[b] = a0.x*w0.x + a0.y*w0.y + a0.z*w0.z + a0.w*w0.w
         + a1.x*w1.x + a1.y*w1.y + a1.z*w1.z + a1.w*w1.w;
  }
  #pragma unroll
  for (int m = 1; m < 64; m <<= 1) {
    #pragma unroll
    for (int b = 0; b < 4; b++) d[b] += __shfl_xor(d[b], m);
  }
  if (lane == 0) {
    float abv = ab[col];
    #pragma unroll
    for (int b = 0; b < 4; b++) styles[b * 2048 + col] = d[b] * WGAIN_C + abv;
  }
}

// ---------------- dcoef: rsqrt(sum_j (W[i,j]*s[b,j])^2 + 1e-8) ----------------
// one wave per (mat,row), all 4 batches (W row read once)
__global__ __launch_bounds__(256) void dcoef_k(const float* __restrict__ qw,
    const float* __restrict__ kw, const float* __restrict__ vw,
    const float* __restrict__ ww, const float* __restrict__ uw,
    const float* __restrict__ styles,
    float* __restrict__ scl_qkv, float* __restrict__ scl_ou) {
  int lane = threadIdx.x & 63;
  int gid = blockIdx.x * 4 + (threadIdx.x >> 6);   // 0..5119
  int mat = gid >> 10;
  int i = gid & 1023;
  const float* W = (mat == 0 ? qw : mat == 1 ? kw : mat == 2 ? vw : mat == 3 ? ww : uw)
                   + (size_t)i * 1024 + lane * 16;
  const float* s = styles + (mat >= 3 ? 1024 : 0) + lane * 16;
  float a[4] = {0.f, 0.f, 0.f, 0.f};
  #pragma unroll
  for (int j = 0; j < 16; j += 4) {
    float4 wv = *(const float4*)(W + j);
    #pragma unroll
    for (int b = 0; b < 4; b++) {
      float4 sv = *(const float4*)(s + b * 2048 + j);
      float m0 = wv.x*sv.x, m1 = wv.y*sv.y, m2 = wv.z*sv.z, m3 = wv.w*sv.w;
      a[b] += m0*m0 + m1*m1 + m2*m2 + m3*m3;
    }
  }
  #pragma unroll
  for (int m = 1; m < 64; m <<= 1) {
    #pragma unroll
    for (int b = 0; b < 4; b++) a[b] += __shfl_xor(a[b], m);
  }
  if (lane == 0) {
    #pragma unroll
    for (int b = 0; b < 4; b++) {
      float d = rsqrtf(a[b] + 1e-8f);
      if (mat == 2) d *= styles[b * 2048 + 1024 + i];   // fold *s2 into v scale
      if (mat < 3) scl_qkv[mat * 4096 + b * 1024 + i] = d;
      else         scl_ou[(mat - 3) * 4096 + b * 1024 + i] = d;
    }
  }
}

// ---------------- x = LN(x * s1) -> bf16 ----------------
__global__ __launch_bounds__(256) void lnorm_k(const float* __restrict__ x,
    const float* __restrict__ styles, u16* __restrict__ xn) {
  int row = blockIdx.x;            // 0..4095
  int b = row >> 10;
  int t = threadIdx.x;
  const float* xr = x + (size_t)row * 1024 + t * 4;
  const float* sr = styles + b * 2048 + t * 4;
  float4 xv = *(const float4*)xr;
  float4 sv = *(const float4*)sr;
  float y0 = xv.x*sv.x, y1 = xv.y*sv.y, y2 = xv.z*sv.z, y3 = xv.w*sv.w;
  float sum = y0 + y1 + y2 + y3;
  float ssq = y0*y0 + y1*y1 + y2*y2 + y3*y3;
  #pragma unroll
  for (int m = 1; m < 64; m <<= 1) { sum += __shfl_xor(sum, m); ssq += __shfl_xor(ssq, m); }
  __shared__ float red[8];
  int wave = t >> 6;
  if ((t & 63) == 0) { red[wave] = sum; red[4 + wave] = ssq; }
  __syncthreads();
  sum = red[0] + red[1] + red[2] + red[3];
  ssq = red[4] + red[5] + red[6] + red[7];
  float mu = sum * (1.f / 1024.f);
  float var = ssq * (1.f / 1024.f) - mu * mu;
  float rs = rsqrtf(var + 1e-5f);
  u16x4 o = { f2bf((y0-mu)*rs), f2bf((y1-mu)*rs), f2bf((y2-mu)*rs), f2bf((y3-mu)*rs) };
  *(u16x4*)(xn + (size_t)row * 1024 + t * 4) = o;
}

// ---------------- convert q/k/v weights f32 -> bf16 ----------------
__global__ __launch_bounds__(256) void convq_k(const float* __restrict__ qw,
    const float* __restrict__ kw, const float* __restrict__ vw, u16* __restrict__ dst) {
  int t = blockIdx.x * 256 + threadIdx.x;
  int e0 = t * 8;
  int mat = e0 >> 20;
  int off = e0 & 1048575;
  const float* src = (mat == 0 ? qw : mat == 1 ? kw : vw) + off;
  float4 a = *(const float4*)src;
  float4 c = *(const float4*)(src + 4);
  u16x4 lo = { f2bf(a.x), f2bf(a.y), f2bf(a.z), f2bf(a.w) };
  u16x4 hi = { f2bf(c.x), f2bf(c.y), f2bf(c.z), f2bf(c.w) };
  *(u16x4*)(dst + e0) = lo;
  *(u16x4*)(dst + e0 + 4) = hi;
}

// ---------------- out-proj weights: prescaled per batch ----------------
__global__ __launch_bounds__(256) void convou_k(const float* __restrict__ ww,
    const float* __restrict__ uw, const float* __restrict__ scl_ou, u16* __restrict__ dst) {
  int t = blockIdx.x * 256 + threadIdx.x;
  int e0 = t * 8;
  int b = e0 >> 21;
  int rem = e0 & 2097151;
  int n = rem >> 11;
  int k0 = rem & 2047;
  int half = k0 >> 10;
  const float* src = half ? uw + (size_t)n * 1024 + (k0 - 1024)
                          : ww + (size_t)n * 1024 + k0;
  float sc = scl_ou[half * 4096 + b * 1024 + n];
  float4 a = *(const float4*)src;
  float4 c = *(const float4*)(src + 4);
  u16x4 lo = { f2bf(a.x*sc), f2bf(a.y*sc), f2bf(a.z*sc), f2bf(a.w*sc) };
  u16x4 hi = { f2bf(c.x*sc), f2bf(c.y*sc), f2bf(c.z*sc), f2bf(c.w*sc) };
  *(u16x4*)(dst + e0) = lo;
  *(u16x4*)(dst + e0 + 4) = hi;
}

// ---------------- QKV GEMM: C = xn @ W^T, 128x128 tile, BK=32, XCD-chunked ----------------
__global__ __launch_bounds__(256) void gemm_qkv_k(const u16* __restrict__ A,
    const u16* __restrict__ Bw, const float* __restrict__ scl_qkv,
    u16* __restrict__ qout, u16* __restrict__ kout, u16* __restrict__ vov,
    u16* __restrict__ vtout) {
  __shared__ u16 Asm[128][32];
  __shared__ u16 Bsm[128][32];
  int tid = threadIdx.x;
  int lane = tid & 63;
  int qi = lane & 15, g = lane >> 4;
  int wave = tid >> 6;
  int wm = wave >> 1, wn = wave & 1;
  int bid = blockIdx.x;                       // 768 blocks
  int swz = (bid & 7) * 96 + (bid >> 3);      // XCD-contiguous tiles
  int m0 = (swz & 31) * 128;
  int n0 = (swz >> 5) * 128;
  f32x4 acc[4][4] = {};
  const u16* ag = A  + (size_t)(m0 + (tid >> 2)) * 1024 + (tid & 3) * 8;
  const u16* bg = Bw + (size_t)(n0 + (tid >> 2)) * 1024 + (tid & 3) * 8;
  u16* as0 = &Asm[0][0] + tid * 8;
  u16* bs0 = &Bsm[0][0] + tid * 8;
  for (int k0 = 0; k0 < 1024; k0 += 32) {
    gl_lds16(ag + k0, as0);
    gl_lds16(ag + 64 * 1024 + k0, as0 + 2048);
    gl_lds16(bg + k0, bs0);
    gl_lds16(bg + 64 * 1024 + k0, bs0 + 2048);
    __syncthreads();
    s16x8 af[4], bf[4];
    #pragma unroll
    for (int i = 0; i < 4; i++) af[i] = *(const s16x8*)&Asm[wm * 64 + i * 16 + qi][g * 8];
    #pragma unroll
    for (int j = 0; j < 4; j++) bf[j] = *(const s16x8*)&Bsm[wn * 64 + j * 16 + qi][g * 8];
    #pragma unroll
    for (int i = 0; i < 4; i++)
      #pragma unroll
      for (int j = 0; j < 4; j++)
        acc[i][j] = __builtin_amdgcn_mfma_f32_16x16x32_bf16(af[i], bf[j], acc[i][j], 0, 0, 0);
    __syncthreads();
  }
  int which = n0 >> 10;           // uniform per block
  int nl0 = n0 & 1023;
  int b = m0 >> 10;
  const float* scl = scl_qkv + which * 4096 + b * 1024;
  u16* outp; int ostride;
  if (which == 0)      { outp = qout; ostride = 1024; }
  else if (which == 1) { outp = kout; ostride = 1024; }
  else                 { outp = vov;  ostride = 2048; }   // v cols of ov buffer
  #pragma unroll
  for (int i = 0; i < 4; i++) {
    int mrow = m0 + wm * 64 + i * 16 + g * 4;
    #pragma unroll
    for (int j = 0; j < 4; j++) {
      int nl = nl0 + wn * 64 + j * 16 + qi;
      float s = scl[nl];
      if (which == 0) s *= SCALE_L2E;   // fold softmax scale + log2e into Q
      u16 b0 = f2bf(acc[i][j][0] * s), b1 = f2bf(acc[i][j][1] * s);
      u16 b2 = f2bf(acc[i][j][2] * s), b3 = f2bf(acc[i][j][3] * s);
      outp[(size_t)(mrow + 0) * ostride + nl] = b0;
      outp[(size_t)(mrow + 1) * ostride + nl] = b1;
      outp[(size_t)(mrow + 2) * ostride + nl] = b2;
      outp[(size_t)(mrow + 3) * ostride + nl] = b3;
      if (which == 2) {
        u16x4 pk = { b0, b1, b2, b3 };
        *(u16x4*)(vtout + (size_t)(b * 1024 + nl) * 1024 + (mrow - b * 1024)) = pk;
      }
    }
  }
}

// ---------------- flash attention ----------------
// 4 waves / block, 64 q rows, KVBLK=64. LDS layouts (all conflict-free):
//  K: pair-interleaved [r=key>>1][slot = ((key&1)*4+dchunk) ^ (r&7)] (row=128B)
//  V^T: [d][slot = schunk ^ (d&7)]          (row=128B)
//  P: per-wave [q][elem ^ ((q&7)*8)]        (row=128B)
// Staged via global_load_lds with pre-swizzled global source addresses.
// Defer-max (THR=8 in log2 units), per-lane lsum, setprio around MFMA.
__global__ __launch_bounds__(256) void attn_k(const u16* __restrict__ q,
    const u16* __restrict__ k, const u16* __restrict__ vt, u16* __restrict__ oout) {
  __shared__ u16 Kl[2][2048];
  __shared__ u16 Vl[2][2048];
  __shared__ u16 Pl[4][1024];
  int tid = threadIdx.x;
  int lane = tid & 63;
  int w = tid >> 6;
  int qi = lane & 15, g = lane >> 4;
  int bid = blockIdx.x;
  int swz = (bid & 7) * 256 + (bid >> 3);   // one head's 16 q-blocks per XCD chunk
  int qblk = swz & 15;
  int bh = swz >> 4;
  int b = bh >> 5, h = bh & 31;
  int q0 = qblk * 64;
  s16x8 qf = *(const s16x8*)(q + (size_t)((b << 10) + q0 + w * 16 + qi) * 1024 + h * 32 + g * 8);
  const u16* kbase = k + (size_t)(b << 10) * 1024 + h * 32;
  const u16* vbase = vt + (size_t)((b << 10) + h * 32) * 1024;
  // K stage: dest (r=tid>>3, slot=tid&7); logical chunk c'=slot^(r&7) -> key=2r+(c'>>2), dch=c'&3
  int kr_ = tid >> 3, ks_ = tid & 7;
  int kcp = ks_ ^ (kr_ & 7);
  int kkey = 2 * kr_ + (kcp >> 2);
  int kdch = kcp & 3;
  // V stage: dest (vr=tid>>3, vc=tid&7); source chunk = vc ^ (vr&7)
  int vr = tid >> 3, vc = tid & 7;
  int vcs = vc ^ (vr & 7);
  u16* Pw = &Pl[w][0];
  int qx8 = (qi & 7) << 3;                  // 3-bit elem XOR (16B granules)
  float mrun = -1e30f, lsum = 0.f;
  f32x4 o0 = {0.f,0.f,0.f,0.f}, o1 = {0.f,0.f,0.f,0.f};
  const f32x4 zero = {0.f,0.f,0.f,0.f};

  gl_lds16(kbase + (size_t)kkey * 1024 + kdch * 8, &Kl[0][0] + tid * 8);
  gl_lds16(vbase + (size_t)vr * 1024 + vcs * 8, &Vl[0][0] + tid * 8);
  __syncthreads();

  for (int it = 0; it < 16; ++it) {
    int nb = it & 1;
    if (it < 15) {
      int ktn = (it + 1) * 64;
      gl_lds16(kbase + (size_t)(ktn + kkey) * 1024 + kdch * 8, &Kl[nb ^ 1][0] + tid * 8);
      gl_lds16(vbase + (size_t)vr * 1024 + ktn + vcs * 8, &Vl[nb ^ 1][0] + tid * 8);
    }
    // QK^T (swapped): sa[kg][r] = S^T[kn = kg*16 + g*4 + r][q = qi], log2-domain
    f32x4 sa[4];
    __builtin_amdgcn_s_setprio(1);
    #pragma unroll
    for (int kg = 0; kg < 4; kg++) {
      int rr = kg * 8 + (qi >> 1);
      int ss = (((qi & 1) << 2) + g) ^ (qi >> 1);
      s16x8 kf = *(const s16x8*)(&Kl[nb][0] + rr * 64 + ss * 8);
      sa[kg] = __builtin_amdgcn_mfma_f32_16x16x32_bf16(kf, qf, zero, 0, 0, 0);
    }
    __builtin_amdgcn_s_setprio(0);
    float cm = fmaxf(
      fmaxf(fmaxf(fmaxf(sa[0][0],sa[0][1]), fmaxf(sa[0][2],sa[0][3])),
            fmaxf(fmaxf(sa[1][0],sa[1][1]), fmaxf(sa[1][2],sa[1][3]))),
      fmaxf(fmaxf(fmaxf(sa[2][0],sa[2][1]), fmaxf(sa[2][2],sa[2][3])),
            fmaxf(fmaxf(sa[3][0],sa[3][1]), fmaxf(sa[3][2],sa[3][3]))));
    if (__any(cm > mrun + 8.0f)) {          // defer-max: rescale only on real growth
      float t = fmaxf(cm, __shfl_xor(cm, 16));
      t = fmaxf(t, __shfl_xor(t, 32));
      float nm = fmaxf(mrun, t);
      float f = __builtin_amdgcn_exp2f(mrun - nm);
      lsum *= f;
      #pragma unroll
      for (int r = 0; r < 4; r++) { o0[r] *= f; o1[r] *= f; }
      mrun = nm;
    }
    float ps = 0.f;
    #pragma unroll
    for (int kg = 0; kg < 4; kg++) {
      float p0 = __builtin_amdgcn_exp2f(sa[kg][0] - mrun);
      float p1 = __builtin_amdgcn_exp2f(sa[kg][1] - mrun);
      float p2 = __builtin_amdgcn_exp2f(sa[kg][2] - mrun);
      float p3 = __builtin_amdgcn_exp2f(sa[kg][3] - mrun);
      ps += (p0 + p1) + (p2 + p3);
      u32x2 pkv = { cvtpk(p0, p1), cvtpk(p2, p3) };
      *(u32x2*)(Pw + qi * 64 + ((kg * 16 + g * 4) ^ qx8)) = pkv;
    }
    lsum += ps;                              // per-lane partial; reduce after loop
    // PV: O^T[d][q] += V^T[d][kn] * P^T[kn][q]
    __builtin_amdgcn_s_setprio(1);
    #pragma unroll
    for (int half = 0; half < 2; half++) {
      int off = (half * 32 + g * 8) ^ qx8;
      s16x8 pf  = *(const s16x8*)(Pw + qi * 64 + off);
      s16x8 va0 = *(const s16x8*)(&Vl[nb][0] + qi * 64 + off);
      s16x8 va1 = *(const s16x8*)(&Vl[nb][0] + (16 + qi) * 64 + off);
      o0 = __builtin_amdgcn_mfma_f32_16x16x32_bf16(va0, pf, o0, 0, 0, 0);
      o1 = __builtin_amdgcn_mfma_f32_16x16x32_bf16(va1, pf, o1, 0, 0, 0);
    }
    __builtin_amdgcn_s_setprio(0);
    __syncthreads();
  }
  lsum += __shfl_xor(lsum, 16);
  lsum += __shfl_xor(lsum, 32);
  float inv = 1.f / lsum;
  u16* orow = oout + (size_t)((b << 10) + q0 + w * 16 + qi) * 2048 + h * 32;
  u16x4 w0 = { f2bf(o0[0]*inv), f2bf(o0[1]*inv), f2bf(o0[2]*inv), f2bf(o0[3]*inv) };
  u16x4 w1 = { f2bf(o1[0]*inv), f2bf(o1[1]*inv), f2bf(o1[2]*inv), f2bf(o1[3]*inv) };
  *(u16x4*)(orow + g * 4) = w0;
  *(u16x4*)(orow + 16 + g * 4) = w1;
}

// ---------------- out GEMM: C = ov @ Bsc[b]^T (K=2048), 128x64 tile, XCD-chunked ----------------
__global__ __launch_bounds__(256) void gemm_out_k(const u16* __restrict__ A,
    const u16* __restrict__ Bw, const float* __restrict__ noi,
    const float* __restrict__ nst, const float* __restrict__ bias,
    float* __restrict__ out) {
  __shared__ u16 Asm[128][32];
  __shared__ u16 Bsm[64][32];
  int tid = threadIdx.x;
  int lane = tid & 63;
  int qi = lane & 15, g = lane >> 4;
  int wave = tid >> 6;            // row band
  int bid = blockIdx.x;                       // 512 blocks
  int swz = (bid & 7) * 64 + (bid >> 3);
  int m0 = (swz & 31) * 128;
  int n0 = (swz >> 5) * 64;
  int b = m0 >> 10;
  f32x4 acc[2][4] = {};
  const u16* ag = A + (size_t)(m0 + (tid >> 2)) * 2048 + (tid & 3) * 8;
  const u16* bg = Bw + (size_t)b * 2048 * 1024 + (size_t)(n0 + (tid >> 2)) * 2048 + (tid & 3) * 8;
  u16* as0 = &Asm[0][0] + tid * 8;
  u16* bs0 = &Bsm[0][0] + tid * 8;
  for (int k0 = 0; k0 < 2048; k0 += 32) {
    gl_lds16(ag + k0, as0);
    gl_lds16(ag + 64 * 2048 + k0, as0 + 2048);
    gl_lds16(bg + k0, bs0);
    __syncthreads();
    s16x8 af[2], bf[4];
    #pragma unroll
    for (int i = 0; i < 2; i++) af[i] = *(const s16x8*)&Asm[wave * 32 + i * 16 + qi][g * 8];
    #pragma unroll
    for (int j = 0; j < 4; j++) bf[j] = *(const s16x8*)&Bsm[j * 16 + qi][g * 8];
    #pragma unroll
    for (int i = 0; i < 2; i++)
      #pragma unroll
      for (int j = 0; j < 4; j++)
        acc[i][j] = __builtin_amdgcn_mfma_f32_16x16x32_bf16(af[i], bf[j], acc[i][j], 0, 0, 0);
    __syncthreads();
  }
  float ns = nst[0];
  #pragma unroll
  for (int i = 0; i < 2; i++) {
    #pragma unroll
    for (int j = 0; j < 4; j++) {
      int n = n0 + j * 16 + qi;
      float bv = bias[n];
      #pragma unroll
      for (int r = 0; r < 4; r++) {
        int mrow = m0 + wave * 32 + i * 16 + g * 4 + r;
        float v = acc[i][j][r] + noi[mrow] * ns + bv;
        v = (v >= 0.f) ? v : 0.2f * v;
        v = fminf(fmaxf(v, -256.f), 256.f);
        out[(size_t)mrow * 1024 + n] = v;
      }
    }
  }
}

extern "C" void kernel_launch(void* const* d_in, const int* in_sizes, int n_in,
                              void* d_out, int out_size, void* d_ws, size_t ws_size,
                              hipStream_t stream) {
  const float* x    = (const float*)d_in[0];
  const float* w    = (const float*)d_in[1];
  const float* aw   = (const float*)d_in[2];
  const float* ab   = (const float*)d_in[3];
  const float* qw   = (const float*)d_in[4];
  const float* kw   = (const float*)d_in[5];
  const float* vw   = (const float*)d_in[6];
  const float* wwp  = (const float*)d_in[7];
  const float* uwp  = (const float*)d_in[8];
  const float* bias = (const float*)d_in[9];
  const float* nst  = (const float*)d_in[10];
  const float* noi  = (const float*)d_in[11];
  float* out = (float*)d_out;

  char* ws = (char*)d_ws;
  float* styles  = (float*)ws;  ws += 8192 * 4;           // [4][2048]
  float* scl_qkv = (float*)ws;  ws += 3 * 4096 * 4;       // [3][4][1024]
  float* scl_ou  = (float*)ws;  ws += 2 * 4096 * 4;       // [2][4][1024]
  u16* xn   = (u16*)ws;         ws += (size_t)4194304 * 2; // [4096][1024]
  u16* wbq  = (u16*)ws;         ws += (size_t)3145728 * 2; // [3][1024][1024]
  u16* wbou = (u16*)ws;         ws += (size_t)8388608 * 2; // [4][1024][2048] prescaled
  u16* qb   = (u16*)ws;         ws += (size_t)4194304 * 2; // [4096][1024]
  u16* kb   = (u16*)ws;         ws += (size_t)4194304 * 2; // [4096][1024]
  u16* vt   = (u16*)ws;         ws += (size_t)4194304 * 2; // [4][1024 hd][1024 s]
  u16* ov   = (u16*)ws;         ws += (size_t)8388608 * 2; // [4096][2048] = [o | v]

  styles_k<<<dim3(512), dim3(256), 0, stream>>>(w, aw, ab, styles);
  dcoef_k<<<dim3(1280), dim3(256), 0, stream>>>(qw, kw, vw, wwp, uwp, styles, scl_qkv, scl_ou);
  lnorm_k<<<dim3(4096), dim3(256), 0, stream>>>(x, styles, xn);
  convq_k<<<dim3(1536), dim3(256), 0, stream>>>(qw, kw, vw, wbq);
  convou_k<<<dim3(4096), dim3(256), 0, stream>>>(wwp, uwp, scl_ou, wbou);
  gemm_qkv_k<<<dim3(768), dim3(256), 0, stream>>>(xn, wbq, scl_qkv, qb, kb, ov + 1024, vt);
  attn_k<<<dim3(2048), dim3(256), 0, stream>>>(qb, kb, vt, ov);
  gemm_out_k<<<dim3(512), dim3(256), 0, stream>>>(ov, wbou, noi, nst, bias, out);
}

// Round 4
// 148.537 us; speedup vs baseline: 1.5900x; 1.0107x over previous
//
#include <hip/hip_runtime.h>

// Encoder layer, MI355X. Pipeline:
//  styles -> dcoef -> lnorm -> convall (q/k/v/w/u weights -> bf16, unscaled)
//  -> QKV GEMM (bf16 MFMA, epilogue scales; Q pre-scaled by SCALE*log2e, writes V^T)
//  -> flash attn (4-wave blocks, KVBLK=128, conflict-minimal LDS swizzles, XCD-chunked)
//  -> out GEMM (dual accumulator over K-halves, wd/ud applied in epilogue).

typedef unsigned short u16;
typedef __attribute__((ext_vector_type(8))) short s16x8;   // 8 bf16 (4 VGPRs)
typedef __attribute__((ext_vector_type(4))) float f32x4;
typedef __attribute__((ext_vector_type(4))) unsigned short u16x4;
typedef __attribute__((ext_vector_type(2))) unsigned int u32x2;

#define WGAIN_C  0.044194173824159216f  // 1/sqrt(512)
// 1/sqrt(32) * log2(e) : folded into Q so attention scores are log2-domain
#define SCALE_L2E (0.17677669529663687f * 1.4426950408889634f)

__device__ __forceinline__ u16 f2bf(float f) {
  union { float f; unsigned u; } v; v.f = f;
  return (u16)((v.u + 0x7FFFu + ((v.u >> 16) & 1u)) >> 16);
}

__device__ __forceinline__ unsigned cvtpk(float lo, float hi) {
  unsigned r;
  asm("v_cvt_pk_bf16_f32 %0, %1, %2" : "=v"(r) : "v"(lo), "v"(hi));
  return r;
}

__device__ __forceinline__ float max3f(float a, float b, float c) {
  return fmaxf(fmaxf(a, b), c);   // clang fuses to v_max3_f32
}

__device__ __forceinline__ void gl_lds16(const u16* g, u16* l) {
  __builtin_amdgcn_global_load_lds(
      (const __attribute__((address_space(1))) unsigned int*)g,
      (__attribute__((address_space(3))) unsigned int*)l, 16, 0, 0);
}

// ---------------- styles = w @ (affine_w.T * WGAIN) + affine_b ----------------
__global__ __launch_bounds__(256) void styles_k(const float* __restrict__ w,
    const float* __restrict__ aw, const float* __restrict__ ab,
    float* __restrict__ styles) {
  int lane = threadIdx.x & 63;
  int col = blockIdx.x * 4 + (threadIdx.x >> 6);   // 0..2047
  const float* awr = aw + (size_t)col * 512 + lane * 8;
  float4 a0 = *(const float4*)awr;
  float4 a1 = *(const float4*)(awr + 4);
  float d[4];
  #pragma unroll
  for (int b = 0; b < 4; b++) {
    const float* wr = w + b * 512 + lane * 8;
    float4 w0 = *(const float4*)wr;
    float4 w1 = *(const float4*)(wr + 4);
    d[b] = a0.x*w0.x + a0.y*w0.y + a0.z*w0.z + a0.w*w0.w
         + a1.x*w1.x + a1.y*w1.y + a1.z*w1.z + a1.w*w1.w;
  }
  #pragma unroll
  for (int m = 1; m < 64; m <<= 1) {
    #pragma unroll
    for (int b = 0; b < 4; b++) d[b] += __shfl_xor(d[b], m);
  }
  if (lane == 0) {
    float abv = ab[col];
    #pragma unroll
    for (int b = 0; b < 4; b++) styles[b * 2048 + col] = d[b] * WGAIN_C + abv;
  }
}

// ---------------- dcoef: rsqrt(sum_j (W[i,j]*s[b,j])^2 + 1e-8) ----------------
__global__ __launch_bounds__(256) void dcoef_k(const float* __restrict__ qw,
    const float* __restrict__ kw, const float* __restrict__ vw,
    const float* __restrict__ ww, const float* __restrict__ uw,
    const float* __restrict__ styles,
    float* __restrict__ scl_qkv, float* __restrict__ scl_ou) {
  int lane = threadIdx.x & 63;
  int gid = blockIdx.x * 4 + (threadIdx.x >> 6);   // 0..5119
  int mat = gid >> 10;
  int i = gid & 1023;
  const float* W = (mat == 0 ? qw : mat == 1 ? kw : mat == 2 ? vw : mat == 3 ? ww : uw)
                   + (size_t)i * 1024 + lane * 16;
  const float* s = styles + (mat >= 3 ? 1024 : 0) + lane * 16;
  float a[4] = {0.f, 0.f, 0.f, 0.f};
  #pragma unroll
  for (int j = 0; j < 16; j += 4) {
    float4 wv = *(const float4*)(W + j);
    #pragma unroll
    for (int b = 0; b < 4; b++) {
      float4 sv = *(const float4*)(s + b * 2048 + j);
      float m0 = wv.x*sv.x, m1 = wv.y*sv.y, m2 = wv.z*sv.z, m3 = wv.w*sv.w;
      a[b] += m0*m0 + m1*m1 + m2*m2 + m3*m3;
    }
  }
  #pragma unroll
  for (int m = 1; m < 64; m <<= 1) {
    #pragma unroll
    for (int b = 0; b < 4; b++) a[b] += __shfl_xor(a[b], m);
  }
  if (lane == 0) {
    #pragma unroll
    for (int b = 0; b < 4; b++) {
      float d = rsqrtf(a[b] + 1e-8f);
      if (mat == 2) d *= styles[b * 2048 + 1024 + i];   // fold *s2 into v scale
      if (mat < 3) scl_qkv[mat * 4096 + b * 1024 + i] = d;
      else         scl_ou[(mat - 3) * 4096 + b * 1024 + i] = d;
    }
  }
}

// ---------------- x = LN(x * s1) -> bf16 ----------------
__global__ __launch_bounds__(256) void lnorm_k(const float* __restrict__ x,
    const float* __restrict__ styles, u16* __restrict__ xn) {
  int row = blockIdx.x;            // 0..4095
  int b = row >> 10;
  int t = threadIdx.x;
  const float* xr = x + (size_t)row * 1024 + t * 4;
  const float* sr = styles + b * 2048 + t * 4;
  float4 xv = *(const float4*)xr;
  float4 sv = *(const float4*)sr;
  float y0 = xv.x*sv.x, y1 = xv.y*sv.y, y2 = xv.z*sv.z, y3 = xv.w*sv.w;
  float sum = y0 + y1 + y2 + y3;
  float ssq = y0*y0 + y1*y1 + y2*y2 + y3*y3;
  #pragma unroll
  for (int m = 1; m < 64; m <<= 1) { sum += __shfl_xor(sum, m); ssq += __shfl_xor(ssq, m); }
  __shared__ float red[8];
  int wave = t >> 6;
  if ((t & 63) == 0) { red[wave] = sum; red[4 + wave] = ssq; }
  __syncthreads();
  sum = red[0] + red[1] + red[2] + red[3];
  ssq = red[4] + red[5] + red[6] + red[7];
  float mu = sum * (1.f / 1024.f);
  float var = ssq * (1.f / 1024.f) - mu * mu;
  float rs = rsqrtf(var + 1e-5f);
  u16x4 o = { f2bf((y0-mu)*rs), f2bf((y1-mu)*rs), f2bf((y2-mu)*rs), f2bf((y3-mu)*rs) };
  *(u16x4*)(xn + (size_t)row * 1024 + t * 4) = o;
}

// ---------------- convert all 5 weight matrices f32 -> bf16 ----------------
// q/k/v -> wbq[mat][n][k]; ww -> wcat[n][0..1023]; uw -> wcat[n][1024..2047]
__global__ __launch_bounds__(256) void convall_k(const float* __restrict__ qw,
    const float* __restrict__ kw, const float* __restrict__ vw,
    const float* __restrict__ ww, const float* __restrict__ uw,
    u16* __restrict__ wbq, u16* __restrict__ wcat) {
  int t = blockIdx.x * 256 + threadIdx.x;    // 655360 threads, 8 elems each
  int e0 = t * 8;
  int mat = e0 >> 20;
  int off = e0 & 1048575;
  const float* src = (mat == 0 ? qw : mat == 1 ? kw : mat == 2 ? vw : mat == 3 ? ww : uw) + off;
  u16* dst;
  if (mat < 3) dst = wbq + e0;
  else {
    int n = off >> 10, kk = off & 1023;
    dst = wcat + (size_t)n * 2048 + (mat == 4 ? 1024 : 0) + kk;
  }
  float4 a = *(const float4*)src;
  float4 c = *(const float4*)(src + 4);
  u16x4 lo = { f2bf(a.x), f2bf(a.y), f2bf(a.z), f2bf(a.w) };
  u16x4 hi = { f2bf(c.x), f2bf(c.y), f2bf(c.z), f2bf(c.w) };
  *(u16x4*)dst = lo;
  *(u16x4*)(dst + 4) = hi;
}

// ---------------- QKV GEMM: C = xn @ W^T, 128x128 tile, BK=32, XCD m-chunked ----------------
__global__ __launch_bounds__(256) void gemm_qkv_k(const u16* __restrict__ A,
    const u16* __restrict__ Bw, const float* __restrict__ scl_qkv,
    u16* __restrict__ qout, u16* __restrict__ kout, u16* __restrict__ vov,
    u16* __restrict__ vtout) {
  __shared__ u16 Asm[128][32];
  __shared__ u16 Bsm[128][32];
  int tid = threadIdx.x;
  int lane = tid & 63;
  int qi = lane & 15, g = lane >> 4;
  int wave = tid >> 6;
  int wm = wave >> 1, wn = wave & 1;
  int bid = blockIdx.x;                       // 768 blocks
  int xcd = bid & 7, idx = bid >> 3;          // XCD owns 4 m-tiles, streams 24 n-tiles
  int m0 = (xcd * 4 + (idx & 3)) * 128;
  int n0 = (idx >> 2) * 128;
  f32x4 acc[4][4] = {};
  const u16* ag = A  + (size_t)(m0 + (tid >> 2)) * 1024 + (tid & 3) * 8;
  const u16* bg = Bw + (size_t)(n0 + (tid >> 2)) * 1024 + (tid & 3) * 8;
  u16* as0 = &Asm[0][0] + tid * 8;
  u16* bs0 = &Bsm[0][0] + tid * 8;
  for (int k0 = 0; k0 < 1024; k0 += 32) {
    gl_lds16(ag + k0, as0);
    gl_lds16(ag + 64 * 1024 + k0, as0 + 2048);
    gl_lds16(bg + k0, bs0);
    gl_lds16(bg + 64 * 1024 + k0, bs0 + 2048);
    __syncthreads();
    s16x8 af[4], bf[4];
    #pragma unroll
    for (int i = 0; i < 4; i++) af[i] = *(const s16x8*)&Asm[wm * 64 + i * 16 + qi][g * 8];
    #pragma unroll
    for (int j = 0; j < 4; j++) bf[j] = *(const s16x8*)&Bsm[wn * 64 + j * 16 + qi][g * 8];
    __builtin_amdgcn_s_setprio(1);
    #pragma unroll
    for (int i = 0; i < 4; i++)
      #pragma unroll
      for (int j = 0; j < 4; j++)
        acc[i][j] = __builtin_amdgcn_mfma_f32_16x16x32_bf16(af[i], bf[j], acc[i][j], 0, 0, 0);
    __builtin_amdgcn_s_setprio(0);
    __syncthreads();
  }
  int which = n0 >> 10;           // uniform per block
  int nl0 = n0 & 1023;
  int b = m0 >> 10;
  const float* scl = scl_qkv + which * 4096 + b * 1024;
  u16* outp; int ostride;
  if (which == 0)      { outp = qout; ostride = 1024; }
  else if (which == 1) { outp = kout; ostride = 1024; }
  else                 { outp = vov;  ostride = 2048; }   // v cols of ov buffer
  #pragma unroll
  for (int i = 0; i < 4; i++) {
    int mrow = m0 + wm * 64 + i * 16 + g * 4;
    #pragma unroll
    for (int j = 0; j < 4; j++) {
      int nl = nl0 + wn * 64 + j * 16 + qi;
      float s = scl[nl];
      if (which == 0) s *= SCALE_L2E;   // fold softmax scale + log2e into Q
      u16 b0 = f2bf(acc[i][j][0] * s), b1 = f2bf(acc[i][j][1] * s);
      u16 b2 = f2bf(acc[i][j][2] * s), b3 = f2bf(acc[i][j][3] * s);
      outp[(size_t)(mrow + 0) * ostride + nl] = b0;
      outp[(size_t)(mrow + 1) * ostride + nl] = b1;
      outp[(size_t)(mrow + 2) * ostride + nl] = b2;
      outp[(size_t)(mrow + 3) * ostride + nl] = b3;
      if (which == 2) {
        u16x4 pk = { b0, b1, b2, b3 };
        *(u16x4*)(vtout + (size_t)(b * 1024 + nl) * 1024 + (mrow - b * 1024)) = pk;
      }
    }
  }
}

// ---------------- flash attention ----------------
// 4 waves / block, 64 q rows, KVBLK=128, 8 iterations. LDS (48KB, 3 blk/CU):
//  K: pair-interleaved [r=key>>1 (64)][slot = ((key&1)*4+dchunk) ^ (r&7)]  8KB x2
//  V^T: [d (32)][slot(16) = schunk ^ ((d&7)<<1)]                           8KB x2
//  P: per-wave [q (16)][elem(128) ^ (q<<3)]                                4KB x4
// Staged via global_load_lds with pre-swizzled global source addresses.
// Defer-max (THR=8 log2-units), per-lane lsum, max3 trees, setprio on MFMA.
__global__ __launch_bounds__(256) void attn_k(const u16* __restrict__ q,
    const u16* __restrict__ k, const u16* __restrict__ vt, u16* __restrict__ oout) {
  __shared__ u16 Kl[2][4096];
  __shared__ u16 Vl[2][4096];
  __shared__ u16 Pl[4][2048];
  int tid = threadIdx.x;
  int lane = tid & 63;
  int w = tid >> 6;
  int qi = lane & 15, g = lane >> 4;
  int bid = blockIdx.x;
  int swz = (bid & 7) * 256 + (bid >> 3);   // one head's 16 q-blocks per XCD chunk
  int qblk = swz & 15;
  int bh = swz >> 4;
  int b = bh >> 5, h = bh & 31;
  int q0 = qblk * 64;
  s16x8 qf = *(const s16x8*)(q + (size_t)((b << 10) + q0 + w * 16 + qi) * 1024 + h * 32 + g * 8);
  const u16* kbase = k + (size_t)(b << 10) * 1024 + h * 32;
  const u16* vbase = vt + (size_t)((b << 10) + h * 32) * 1024;
  // K stage: dest granule gi=tid -> r=gi>>3 (0..31), slot=gi&7; round2 = +64 keys
  {
  }
  int kr_ = tid >> 3, ks_ = tid & 7;
  int kcp = ks_ ^ (kr_ & 7);
  int kkey = 2 * kr_ + (kcp >> 2);          // 0..63
  int kdch = kcp & 3;
  // V stage: dest granule gi=tid -> d=gi>>4 (0..15), slot=gi&15; round2 = +16 d rows
  int vd = tid >> 4, vs = tid & 15;
  int vsch = vs ^ ((vd & 7) << 1);
  const u16* ksrc1 = kbase + (size_t)kkey * 1024 + kdch * 8;
  const u16* vsrc1 = vbase + (size_t)vd * 1024 + vsch * 8;
  u16* Pw = &Pl[w][0];
  int qx = qi << 3;                          // P elem-XOR
  float mrun = -1e30f, lsum = 0.f;
  f32x4 o0 = {0.f,0.f,0.f,0.f}, o1 = {0.f,0.f,0.f,0.f};
  const f32x4 zero = {0.f,0.f,0.f,0.f};

  gl_lds16(ksrc1, &Kl[0][0] + tid * 8);
  gl_lds16(ksrc1 + 64 * 1024, &Kl[0][0] + 2048 + tid * 8);
  gl_lds16(vsrc1, &Vl[0][0] + tid * 8);
  gl_lds16(vsrc1 + 16 * 1024, &Vl[0][0] + 2048 + tid * 8);
  __syncthreads();

  for (int it = 0; it < 8; ++it) {
    int nb = it & 1;
    if (it < 7) {
      const u16* kn_ = ksrc1 + (size_t)(it + 1) * 128 * 1024;
      const u16* vn_ = vsrc1 + (it + 1) * 128;
      gl_lds16(kn_, &Kl[nb ^ 1][0] + tid * 8);
      gl_lds16(kn_ + 64 * 1024, &Kl[nb ^ 1][0] + 2048 + tid * 8);
      gl_lds16(vn_, &Vl[nb ^ 1][0] + tid * 8);
      gl_lds16(vn_ + 16 * 1024, &Vl[nb ^ 1][0] + 2048 + tid * 8);
    }
    // QK^T (swapped): sa[kg][r] = S^T[kn = kg*16 + g*4 + r][q = qi], log2-domain
    f32x4 sa[8];
    __builtin_amdgcn_s_setprio(1);
    #pragma unroll
    for (int kg = 0; kg < 8; kg++) {
      int rr = kg * 8 + (qi >> 1);
      int ss = (((qi & 1) << 2) + g) ^ (qi >> 1);
      s16x8 kf = *(const s16x8*)(&Kl[nb][0] + rr * 64 + ss * 8);
      sa[kg] = __builtin_amdgcn_mfma_f32_16x16x32_bf16(kf, qf, zero, 0, 0, 0);
    }
    __builtin_amdgcn_s_setprio(0);
    float cm = -1e30f;
    #pragma unroll
    for (int kg = 0; kg < 8; kg++)
      cm = max3f(sa[kg][0], sa[kg][1], max3f(sa[kg][2], sa[kg][3], cm));
    if (__any(cm > mrun + 8.0f)) {          // defer-max: rescale only on real growth
      float t = fmaxf(cm, __shfl_xor(cm, 16));
      t = fmaxf(t, __shfl_xor(t, 32));
      float nm = fmaxf(mrun, t);
      float f = __builtin_amdgcn_exp2f(mrun - nm);
      lsum *= f;
      #pragma unroll
      for (int r = 0; r < 4; r++) { o0[r] *= f; o1[r] *= f; }
      mrun = nm;
    }
    float ps0 = 0.f, ps1 = 0.f;
    #pragma unroll
    for (int kg = 0; kg < 8; kg++) {
      float p0 = __builtin_amdgcn_exp2f(sa[kg][0] - mrun);
      float p1 = __builtin_amdgcn_exp2f(sa[kg][1] - mrun);
      float p2 = __builtin_amdgcn_exp2f(sa[kg][2] - mrun);
      float p3 = __builtin_amdgcn_exp2f(sa[kg][3] - mrun);
      ps0 += p0 + p1; ps1 += p2 + p3;
      u32x2 pkv = { cvtpk(p0, p1), cvtpk(p2, p3) };
      *(u32x2*)(Pw + qi * 128 + ((kg * 16 + g * 4) ^ qx)) = pkv;
    }
    lsum += ps0 + ps1;                       // per-lane partial; reduce after loop
    // PV: O^T[d][q] += V^T[d][kn] * P^T[kn][q], 4 kn-slices of 32
    __builtin_amdgcn_s_setprio(1);
    #pragma unroll
    for (int t4 = 0; t4 < 4; t4++) {
      s16x8 pf  = *(const s16x8*)(Pw + qi * 128 + ((t4 * 32 + g * 8) ^ qx));
      int voff = ((t4 * 4 + g) ^ ((qi & 7) << 1)) * 8;
      s16x8 va0 = *(const s16x8*)(&Vl[nb][0] + qi * 128 + voff);
      s16x8 va1 = *(const s16x8*)(&Vl[nb][0] + (16 + qi) * 128 + voff);
      o0 = __builtin_amdgcn_mfma_f32_16x16x32_bf16(va0, pf, o0, 0, 0, 0);
      o1 = __builtin_amdgcn_mfma_f32_16x16x32_bf16(va1, pf, o1, 0, 0, 0);
    }
    __builtin_amdgcn_s_setprio(0);
    __syncthreads();
  }
  lsum += __shfl_xor(lsum, 16);
  lsum += __shfl_xor(lsum, 32);
  float inv = 1.f / lsum;
  u16* orow = oout + (size_t)((b << 10) + q0 + w * 16 + qi) * 2048 + h * 32;
  u16x4 w0 = { f2bf(o0[0]*inv), f2bf(o0[1]*inv), f2bf(o0[2]*inv), f2bf(o0[3]*inv) };
  u16x4 w1 = { f2bf(o1[0]*inv), f2bf(o1[1]*inv), f2bf(o1[2]*inv), f2bf(o1[3]*inv) };
  *(u16x4*)(orow + g * 4) = w0;
  *(u16x4*)(orow + 16 + g * 4) = w1;
}

// ---------------- out GEMM: dual-acc over K-halves, shared weights ----------------
// C = (o @ Ww^T)*wd + (v @ Uw^T)*ud; A = ov [4096][2048], B = wcat [1024][2048]
__global__ __launch_bounds__(256) void gemm_out_k(const u16* __restrict__ A,
    const u16* __restrict__ Bw, const float* __restrict__ scl_ou,
    const float* __restrict__ noi, const float* __restrict__ nst,
    const float* __restrict__ bias, float* __restrict__ out) {
  __shared__ u16 Asm[128][32];
  __shared__ u16 Bsm[64][32];
  int tid = threadIdx.x;
  int lane = tid & 63;
  int qi = lane & 15, g = lane >> 4;
  int wave = tid >> 6;            // row band
  int bid = blockIdx.x;                       // 512 blocks
  int xcd = bid & 7, idx = bid >> 3;          // XCD owns 4 m-tiles, streams 16 n-tiles
  int m0 = (xcd * 4 + (idx & 3)) * 128;
  int n0 = (idx >> 2) * 64;
  int b = m0 >> 10;
  f32x4 accW[2][4] = {}, accV[2][4] = {};
  const u16* ag = A + (size_t)(m0 + (tid >> 2)) * 2048 + (tid & 3) * 8;
  const u16* bg = Bw + (size_t)(n0 + (tid >> 2)) * 2048 + (tid & 3) * 8;
  u16* as0 = &Asm[0][0] + tid * 8;
  u16* bs0 = &Bsm[0][0] + tid * 8;
  #pragma unroll 1
  for (int half = 0; half < 2; half++) {
    f32x4 (*acc)[4] = half ? accV : accW;
    int kbeg = half * 1024, kend = kbeg + 1024;
    for (int k0 = kbeg; k0 < kend; k0 += 32) {
      gl_lds16(ag + k0, as0);
      gl_lds16(ag + 64 * 2048 + k0, as0 + 2048);
      gl_lds16(bg + k0, bs0);
      __syncthreads();
      s16x8 af[2], bf[4];
      #pragma unroll
      for (int i = 0; i < 2; i++) af[i] = *(const s16x8*)&Asm[wave * 32 + i * 16 + qi][g * 8];
      #pragma unroll
      for (int j = 0; j < 4; j++) bf[j] = *(const s16x8*)&Bsm[j * 16 + qi][g * 8];
      __builtin_amdgcn_s_setprio(1);
      #pragma unroll
      for (int i = 0; i < 2; i++)
        #pragma unroll
        for (int j = 0; j < 4; j++)
          acc[i][j] = __builtin_amdgcn_mfma_f32_16x16x32_bf16(af[i], bf[j], acc[i][j], 0, 0, 0);
      __builtin_amdgcn_s_setprio(0);
      __syncthreads();
    }
  }
  float ns = nst[0];
  #pragma unroll
  for (int i = 0; i < 2; i++) {
    #pragma unroll
    for (int j = 0; j < 4; j++) {
      int n = n0 + j * 16 + qi;
      float bv = bias[n];
      float wd = scl_ou[b * 1024 + n];
      float ud = scl_ou[4096 + b * 1024 + n];
      #pragma unroll
      for (int r = 0; r < 4; r++) {
        int mrow = m0 + wave * 32 + i * 16 + g * 4 + r;
        float v = accW[i][j][r] * wd + accV[i][j][r] * ud + noi[mrow] * ns + bv;
        v = (v >= 0.f) ? v : 0.2f * v;
        v = fminf(fmaxf(v, -256.f), 256.f);
        out[(size_t)mrow * 1024 + n] = v;
      }
    }
  }
}

extern "C" void kernel_launch(void* const* d_in, const int* in_sizes, int n_in,
                              void* d_out, int out_size, void* d_ws, size_t ws_size,
                              hipStream_t stream) {
  const float* x    = (const float*)d_in[0];
  const float* w    = (const float*)d_in[1];
  const float* aw   = (const float*)d_in[2];
  const float* ab   = (const float*)d_in[3];
  const float* qw   = (const float*)d_in[4];
  const float* kw   = (const float*)d_in[5];
  const float* vw   = (const float*)d_in[6];
  const float* wwp  = (const float*)d_in[7];
  const float* uwp  = (const float*)d_in[8];
  const float* bias = (const float*)d_in[9];
  const float* nst  = (const float*)d_in[10];
  const float* noi  = (const float*)d_in[11];
  float* out = (float*)d_out;

  char* ws = (char*)d_ws;
  float* styles  = (float*)ws;  ws += 8192 * 4;           // [4][2048]
  float* scl_qkv = (float*)ws;  ws += 3 * 4096 * 4;       // [3][4][1024]
  float* scl_ou  = (float*)ws;  ws += 2 * 4096 * 4;       // [2][4][1024]
  u16* xn   = (u16*)ws;         ws += (size_t)4194304 * 2; // [4096][1024]
  u16* wbq  = (u16*)ws;         ws += (size_t)3145728 * 2; // [3][1024][1024]
  u16* wcat = (u16*)ws;         ws += (size_t)2097152 * 2; // [1024][2048] = [Ww|Uw]
  u16* qb   = (u16*)ws;         ws += (size_t)4194304 * 2; // [4096][1024]
  u16* kb   = (u16*)ws;         ws += (size_t)4194304 * 2; // [4096][1024]
  u16* vt   = (u16*)ws;         ws += (size_t)4194304 * 2; // [4][1024 hd][1024 s]
  u16* ov   = (u16*)ws;         ws += (size_t)8388608 * 2; // [4096][2048] = [o | v]

  styles_k<<<dim3(512), dim3(256), 0, stream>>>(w, aw, ab, styles);
  dcoef_k<<<dim3(1280), dim3(256), 0, stream>>>(qw, kw, vw, wwp, uwp, styles, scl_qkv, scl_ou);
  lnorm_k<<<dim3(4096), dim3(256), 0, stream>>>(x, styles, xn);
  convall_k<<<dim3(2560), dim3(256), 0, stream>>>(qw, kw, vw, wwp, uwp, wbq, wcat);
  gemm_qkv_k<<<dim3(768), dim3(256), 0, stream>>>(xn, wbq, scl_qkv, qb, kb, ov + 1024, vt);
  attn_k<<<dim3(2048), dim3(256), 0, stream>>>(qb, kb, vt, ov);
  gemm_out_k<<<dim3(512), dim3(256), 0, stream>>>(ov, wcat, scl_ou, noi, nst, bias, out);
}

// Round 5
// 130.719 us; speedup vs baseline: 1.8068x; 1.1363x over previous
//
#include <hip/hip_runtime.h>

// Encoder layer, MI355X. Pipeline:
//  styles -> dcoef -> lnorm -> convall (q/k/v/w/u weights -> bf16, unscaled)
//  -> QKV GEMM (bf16 MFMA, epilogue scales; Q pre-scaled by SCALE*log2e, writes V^T)
//  -> flash attn (4 waves, KVBLK=64, P-free via K-permutation, 16KB LDS, 8 blk/CU)
//  -> out GEMM (BK=64, swizzled LDS, dual accumulator, wd/ud in epilogue).

typedef unsigned short u16;
typedef __attribute__((ext_vector_type(8))) short s16x8;   // 8 bf16 (4 VGPRs)
typedef __attribute__((ext_vector_type(4))) float f32x4;
typedef __attribute__((ext_vector_type(4))) unsigned short u16x4;
typedef __attribute__((ext_vector_type(4))) unsigned int u32x4;

#define WGAIN_C  0.044194173824159216f  // 1/sqrt(512)
// 1/sqrt(32) * log2(e) : folded into Q so attention scores are log2-domain
#define SCALE_L2E (0.17677669529663687f * 1.4426950408889634f)

__device__ __forceinline__ u16 f2bf(float f) {
  union { float f; unsigned u; } v; v.f = f;
  return (u16)((v.u + 0x7FFFu + ((v.u >> 16) & 1u)) >> 16);
}

__device__ __forceinline__ unsigned cvtpk(float lo, float hi) {
  unsigned r;
  asm("v_cvt_pk_bf16_f32 %0, %1, %2" : "=v"(r) : "v"(lo), "v"(hi));
  return r;
}

__device__ __forceinline__ float max3f(float a, float b, float c) {
  return fmaxf(fmaxf(a, b), c);   // clang fuses to v_max3_f32
}

__device__ __forceinline__ void gl_lds16(const u16* g, u16* l) {
  __builtin_amdgcn_global_load_lds(
      (const __attribute__((address_space(1))) unsigned int*)g,
      (__attribute__((address_space(3))) unsigned int*)l, 16, 0, 0);
}

// ---------------- styles = w @ (affine_w.T * WGAIN) + affine_b ----------------
__global__ __launch_bounds__(256) void styles_k(const float* __restrict__ w,
    const float* __restrict__ aw, const float* __restrict__ ab,
    float* __restrict__ styles) {
  int lane = threadIdx.x & 63;
  int col = blockIdx.x * 4 + (threadIdx.x >> 6);   // 0..2047
  const float* awr = aw + (size_t)col * 512 + lane * 8;
  float4 a0 = *(const float4*)awr;
  float4 a1 = *(const float4*)(awr + 4);
  float d[4];
  #pragma unroll
  for (int b = 0; b < 4; b++) {
    const float* wr = w + b * 512 + lane * 8;
    float4 w0 = *(const float4*)wr;
    float4 w1 = *(const float4*)(wr + 4);
    d[b] = a0.x*w0.x + a0.y*w0.y + a0.z*w0.z + a0.w*w0.w
         + a1.x*w1.x + a1.y*w1.y + a1.z*w1.z + a1.w*w1.w;
  }
  #pragma unroll
  for (int m = 1; m < 64; m <<= 1) {
    #pragma unroll
    for (int b = 0; b < 4; b++) d[b] += __shfl_xor(d[b], m);
  }
  if (lane == 0) {
    float abv = ab[col];
    #pragma unroll
    for (int b = 0; b < 4; b++) styles[b * 2048 + col] = d[b] * WGAIN_C + abv;
  }
}

// ---------------- dcoef: rsqrt(sum_j (W[i,j]*s[b,j])^2 + 1e-8) ----------------
__global__ __launch_bounds__(256) void dcoef_k(const float* __restrict__ qw,
    const float* __restrict__ kw, const float* __restrict__ vw,
    const float* __restrict__ ww, const float* __restrict__ uw,
    const float* __restrict__ styles,
    float* __restrict__ scl_qkv, float* __restrict__ scl_ou) {
  int lane = threadIdx.x & 63;
  int gid = blockIdx.x * 4 + (threadIdx.x >> 6);   // 0..5119
  int mat = gid >> 10;
  int i = gid & 1023;
  const float* W = (mat == 0 ? qw : mat == 1 ? kw : mat == 2 ? vw : mat == 3 ? ww : uw)
                   + (size_t)i * 1024 + lane * 16;
  const float* s = styles + (mat >= 3 ? 1024 : 0) + lane * 16;
  float a[4] = {0.f, 0.f, 0.f, 0.f};
  #pragma unroll
  for (int j = 0; j < 16; j += 4) {
    float4 wv = *(const float4*)(W + j);
    #pragma unroll
    for (int b = 0; b < 4; b++) {
      float4 sv = *(const float4*)(s + b * 2048 + j);
      float m0 = wv.x*sv.x, m1 = wv.y*sv.y, m2 = wv.z*sv.z, m3 = wv.w*sv.w;
      a[b] += m0*m0 + m1*m1 + m2*m2 + m3*m3;
    }
  }
  #pragma unroll
  for (int m = 1; m < 64; m <<= 1) {
    #pragma unroll
    for (int b = 0; b < 4; b++) a[b] += __shfl_xor(a[b], m);
  }
  if (lane == 0) {
    #pragma unroll
    for (int b = 0; b < 4; b++) {
      float d = rsqrtf(a[b] + 1e-8f);
      if (mat == 2) d *= styles[b * 2048 + 1024 + i];   // fold *s2 into v scale
      if (mat < 3) scl_qkv[mat * 4096 + b * 1024 + i] = d;
      else         scl_ou[(mat - 3) * 4096 + b * 1024 + i] = d;
    }
  }
}

// ---------------- x = LN(x * s1) -> bf16 ----------------
__global__ __launch_bounds__(256) void lnorm_k(const float* __restrict__ x,
    const float* __restrict__ styles, u16* __restrict__ xn) {
  int row = blockIdx.x;            // 0..4095
  int b = row >> 10;
  int t = threadIdx.x;
  const float* xr = x + (size_t)row * 1024 + t * 4;
  const float* sr = styles + b * 2048 + t * 4;
  float4 xv = *(const float4*)xr;
  float4 sv = *(const float4*)sr;
  float y0 = xv.x*sv.x, y1 = xv.y*sv.y, y2 = xv.z*sv.z, y3 = xv.w*sv.w;
  float sum = y0 + y1 + y2 + y3;
  float ssq = y0*y0 + y1*y1 + y2*y2 + y3*y3;
  #pragma unroll
  for (int m = 1; m < 64; m <<= 1) { sum += __shfl_xor(sum, m); ssq += __shfl_xor(ssq, m); }
  __shared__ float red[8];
  int wave = t >> 6;
  if ((t & 63) == 0) { red[wave] = sum; red[4 + wave] = ssq; }
  __syncthreads();
  sum = red[0] + red[1] + red[2] + red[3];
  ssq = red[4] + red[5] + red[6] + red[7];
  float mu = sum * (1.f / 1024.f);
  float var = ssq * (1.f / 1024.f) - mu * mu;
  float rs = rsqrtf(var + 1e-5f);
  u16x4 o = { f2bf((y0-mu)*rs), f2bf((y1-mu)*rs), f2bf((y2-mu)*rs), f2bf((y3-mu)*rs) };
  *(u16x4*)(xn + (size_t)row * 1024 + t * 4) = o;
}

// ---------------- convert all 5 weight matrices f32 -> bf16 ----------------
__global__ __launch_bounds__(256) void convall_k(const float* __restrict__ qw,
    const float* __restrict__ kw, const float* __restrict__ vw,
    const float* __restrict__ ww, const float* __restrict__ uw,
    u16* __restrict__ wbq, u16* __restrict__ wcat) {
  int t = blockIdx.x * 256 + threadIdx.x;
  int e0 = t * 8;
  int mat = e0 >> 20;
  int off = e0 & 1048575;
  const float* src = (mat == 0 ? qw : mat == 1 ? kw : mat == 2 ? vw : mat == 3 ? ww : uw) + off;
  u16* dst;
  if (mat < 3) dst = wbq + e0;
  else {
    int n = off >> 10, kk = off & 1023;
    dst = wcat + (size_t)n * 2048 + (mat == 4 ? 1024 : 0) + kk;
  }
  float4 a = *(const float4*)src;
  float4 c = *(const float4*)(src + 4);
  u16x4 lo = { f2bf(a.x), f2bf(a.y), f2bf(a.z), f2bf(a.w) };
  u16x4 hi = { f2bf(c.x), f2bf(c.y), f2bf(c.z), f2bf(c.w) };
  *(u16x4*)dst = lo;
  *(u16x4*)(dst + 4) = hi;
}

// ---------------- QKV GEMM: C = xn @ W^T, 128x128 tile, BK=32, XCD m-chunked ----------------
__global__ __launch_bounds__(256) void gemm_qkv_k(const u16* __restrict__ A,
    const u16* __restrict__ Bw, const float* __restrict__ scl_qkv,
    u16* __restrict__ qout, u16* __restrict__ kout, u16* __restrict__ vov,
    u16* __restrict__ vtout) {
  __shared__ u16 Asm[128][32];
  __shared__ u16 Bsm[128][32];
  int tid = threadIdx.x;
  int lane = tid & 63;
  int qi = lane & 15, g = lane >> 4;
  int wave = tid >> 6;
  int wm = wave >> 1, wn = wave & 1;
  int bid = blockIdx.x;                       // 768 blocks
  int xcd = bid & 7, idx = bid >> 3;          // XCD owns 4 m-tiles, streams 24 n-tiles
  int m0 = (xcd * 4 + (idx & 3)) * 128;
  int n0 = (idx >> 2) * 128;
  f32x4 acc[4][4] = {};
  const u16* ag = A  + (size_t)(m0 + (tid >> 2)) * 1024 + (tid & 3) * 8;
  const u16* bg = Bw + (size_t)(n0 + (tid >> 2)) * 1024 + (tid & 3) * 8;
  u16* as0 = &Asm[0][0] + tid * 8;
  u16* bs0 = &Bsm[0][0] + tid * 8;
  for (int k0 = 0; k0 < 1024; k0 += 32) {
    gl_lds16(ag + k0, as0);
    gl_lds16(ag + 64 * 1024 + k0, as0 + 2048);
    gl_lds16(bg + k0, bs0);
    gl_lds16(bg + 64 * 1024 + k0, bs0 + 2048);
    __syncthreads();
    s16x8 af[4], bf[4];
    #pragma unroll
    for (int i = 0; i < 4; i++) af[i] = *(const s16x8*)&Asm[wm * 64 + i * 16 + qi][g * 8];
    #pragma unroll
    for (int j = 0; j < 4; j++) bf[j] = *(const s16x8*)&Bsm[wn * 64 + j * 16 + qi][g * 8];
    __builtin_amdgcn_s_setprio(1);
    #pragma unroll
    for (int i = 0; i < 4; i++)
      #pragma unroll
      for (int j = 0; j < 4; j++)
        acc[i][j] = __builtin_amdgcn_mfma_f32_16x16x32_bf16(af[i], bf[j], acc[i][j], 0, 0, 0);
    __builtin_amdgcn_s_setprio(0);
    __syncthreads();
  }
  int which = n0 >> 10;           // uniform per block
  int nl0 = n0 & 1023;
  int b = m0 >> 10;
  const float* scl = scl_qkv + which * 4096 + b * 1024;
  u16* outp; int ostride;
  if (which == 0)      { outp = qout; ostride = 1024; }
  else if (which == 1) { outp = kout; ostride = 1024; }
  else                 { outp = vov;  ostride = 2048; }   // v cols of ov buffer
  #pragma unroll
  for (int i = 0; i < 4; i++) {
    int mrow = m0 + wm * 64 + i * 16 + g * 4;
    #pragma unroll
    for (int j = 0; j < 4; j++) {
      int nl = nl0 + wn * 64 + j * 16 + qi;
      float s = scl[nl];
      if (which == 0) s *= SCALE_L2E;   // fold softmax scale + log2e into Q
      u16 b0 = f2bf(acc[i][j][0] * s), b1 = f2bf(acc[i][j][1] * s);
      u16 b2 = f2bf(acc[i][j][2] * s), b3 = f2bf(acc[i][j][3] * s);
      outp[(size_t)(mrow + 0) * ostride + nl] = b0;
      outp[(size_t)(mrow + 1) * ostride + nl] = b1;
      outp[(size_t)(mrow + 2) * ostride + nl] = b2;
      outp[(size_t)(mrow + 3) * ostride + nl] = b3;
      if (which == 2) {
        u16x4 pk = { b0, b1, b2, b3 };
        *(u16x4*)(vtout + (size_t)(b * 1024 + nl) * 1024 + (mrow - b * 1024)) = pk;
      }
    }
  }
}

// ---------------- flash attention (P-free) ----------------
// 4 waves / block, 64 q rows, KVBLK=64, 16 iters, 16KB LDS -> 8 blocks/CU.
// K staged with key-permutation pi(h*32+u*16+g*4+v)=h*32+g*8+u*4+v so each
// lane's packed exp2 words ARE its PV b-fragment (no P LDS, no cross-lane).
//  K LDS: [r=klog>>1 (32)][slot = ((klog&1)*4+dch) ^ (r&7)], 128B rows
//  V LDS: [d (32)][slot(8) = schunk ^ (d&7)], 128B rows
__global__ __launch_bounds__(256, 8) void attn_k(const u16* __restrict__ q,
    const u16* __restrict__ k, const u16* __restrict__ vt, u16* __restrict__ oout) {
  __shared__ u16 Kl[2][2048];
  __shared__ u16 Vl[2][2048];
  int tid = threadIdx.x;
  int lane = tid & 63;
  int w = tid >> 6;
  int qi = lane & 15, g = lane >> 4;
  int bid = blockIdx.x;
  int swz = (bid & 7) * 256 + (bid >> 3);   // one head's 16 q-blocks per XCD chunk
  int qblk = swz & 15;
  int bh = swz >> 4;
  int b = bh >> 5, h = bh & 31;
  int q0 = qblk * 64;
  s16x8 qf = *(const s16x8*)(q + (size_t)((b << 10) + q0 + w * 16 + qi) * 1024 + h * 32 + g * 8);
  const u16* kbase = k + (size_t)(b << 10) * 1024 + h * 32;
  const u16* vbase = vt + (size_t)((b << 10) + h * 32) * 1024;
  // K stage: dest granule tid -> r=tid>>3, slot=tid&7; c'=slot^(r&7);
  // logical key klog = 2r+(c'>>2), dchunk = c'&3; physical key = pi(klog)
  int kr_ = tid >> 3, ks_ = tid & 7;
  int kcp = ks_ ^ (kr_ & 7);
  int klog = 2 * kr_ + (kcp >> 2);
  int kdch = kcp & 3;
  int kphys = (klog & 32) + ((klog >> 2) & 3) * 8 + ((klog >> 4) & 1) * 4 + (klog & 3);
  // V stage: dest granule tid -> d=tid>>3, slot=tid&7; src granule = slot^(d&7)
  int vd = tid >> 3, vs = tid & 7;
  int vsch = vs ^ (vd & 7);
  const u16* ksrc1 = kbase + (size_t)kphys * 1024 + kdch * 8;
  const u16* vsrc1 = vbase + (size_t)vd * 1024 + vsch * 8;
  float mrun = -1e30f, lsum = 0.f;
  f32x4 o0 = {0.f,0.f,0.f,0.f}, o1 = {0.f,0.f,0.f,0.f};
  const f32x4 zero = {0.f,0.f,0.f,0.f};

  gl_lds16(ksrc1, &Kl[0][0] + tid * 8);
  gl_lds16(vsrc1, &Vl[0][0] + tid * 8);
  __syncthreads();

  for (int it = 0; it < 16; ++it) {
    int nb = it & 1;
    if (it < 15) {
      gl_lds16(ksrc1 + (size_t)(it + 1) * 64 * 1024, &Kl[nb ^ 1][0] + tid * 8);
      gl_lds16(vsrc1 + (it + 1) * 64, &Vl[nb ^ 1][0] + tid * 8);
    }
    // QK^T (swapped): sa[kg][r] = S^T[klog = kg*16 + g*4 + r][q = qi], log2-domain
    f32x4 sa[4];
    __builtin_amdgcn_s_setprio(1);
    #pragma unroll
    for (int kg = 0; kg < 4; kg++) {
      int rr = kg * 8 + (qi >> 1);
      int ss = (((qi & 1) << 2) + g) ^ (qi >> 1);
      s16x8 kf = *(const s16x8*)(&Kl[nb][0] + rr * 64 + ss * 8);
      sa[kg] = __builtin_amdgcn_mfma_f32_16x16x32_bf16(kf, qf, zero, 0, 0, 0);
    }
    __builtin_amdgcn_s_setprio(0);
    float cm = -1e30f;
    #pragma unroll
    for (int kg = 0; kg < 4; kg++)
      cm = max3f(sa[kg][0], sa[kg][1], max3f(sa[kg][2], sa[kg][3], cm));
    if (__any(cm > mrun + 8.0f)) {          // defer-max: rescale only on real growth
      float t = fmaxf(cm, __shfl_xor(cm, 16));
      t = fmaxf(t, __shfl_xor(t, 32));
      float nm = fmaxf(mrun, t);
      float f = __builtin_amdgcn_exp2f(mrun - nm);
      lsum *= f;
      #pragma unroll
      for (int r = 0; r < 4; r++) { o0[r] *= f; o1[r] *= f; }
      mrun = nm;
    }
    unsigned pwa[4], pwb[4];
    float ps = 0.f;
    #pragma unroll
    for (int kg = 0; kg < 4; kg++) {
      float p0 = __builtin_amdgcn_exp2f(sa[kg][0] - mrun);
      float p1 = __builtin_amdgcn_exp2f(sa[kg][1] - mrun);
      float p2 = __builtin_amdgcn_exp2f(sa[kg][2] - mrun);
      float p3 = __builtin_amdgcn_exp2f(sa[kg][3] - mrun);
      ps += (p0 + p1) + (p2 + p3);
      pwa[kg] = cvtpk(p0, p1);
      pwb[kg] = cvtpk(p2, p3);
    }
    lsum += ps;                              // per-lane partial; reduce after loop
    // PV: O^T[d][q] += V^T[d][kn] * P[q][kn]; pf = own packed words (pi-aligned)
    __builtin_amdgcn_s_setprio(1);
    #pragma unroll
    for (int h2 = 0; h2 < 2; h2++) {
      union { u32x4 d; s16x8 v; } pu;
      pu.d = (u32x4){ pwa[2*h2], pwb[2*h2], pwa[2*h2+1], pwb[2*h2+1] };
      int vg = ((h2 * 4 + g) ^ (qi & 7)) * 8;
      s16x8 va0 = *(const s16x8*)(&Vl[nb][0] + qi * 64 + vg);
      s16x8 va1 = *(const s16x8*)(&Vl[nb][0] + (16 + qi) * 64 + vg);
      o0 = __builtin_amdgcn_mfma_f32_16x16x32_bf16(va0, pu.v, o0, 0, 0, 0);
      o1 = __builtin_amdgcn_mfma_f32_16x16x32_bf16(va1, pu.v, o1, 0, 0, 0);
    }
    __builtin_amdgcn_s_setprio(0);
    __syncthreads();
  }
  lsum += __shfl_xor(lsum, 16);
  lsum += __shfl_xor(lsum, 32);
  float inv = 1.f / lsum;
  u16* orow = oout + (size_t)((b << 10) + q0 + w * 16 + qi) * 2048 + h * 32;
  u16x4 w0 = { f2bf(o0[0]*inv), f2bf(o0[1]*inv), f2bf(o0[2]*inv), f2bf(o0[3]*inv) };
  u16x4 w1 = { f2bf(o1[0]*inv), f2bf(o1[1]*inv), f2bf(o1[2]*inv), f2bf(o1[3]*inv) };
  *(u16x4*)(orow + g * 4) = w0;
  *(u16x4*)(orow + 16 + g * 4) = w1;
}

// ---------------- out GEMM: BK=64, swizzled LDS, dual-acc over K-halves ----------------
// C = (o @ Ww^T)*wd + (v @ Uw^T)*ud; A = ov [4096][2048], B = wcat [1024][2048]
__global__ __launch_bounds__(256) void gemm_out_k(const u16* __restrict__ A,
    const u16* __restrict__ Bw, const float* __restrict__ scl_ou,
    const float* __restrict__ noi, const float* __restrict__ nst,
    const float* __restrict__ bias, float* __restrict__ out) {
  __shared__ u16 Asm[128 * 64];   // [row][granule ^ (row&7)]
  __shared__ u16 Bsm[64 * 64];
  int tid = threadIdx.x;
  int lane = tid & 63;
  int qi = lane & 15, g = lane >> 4;
  int wave = tid >> 6;            // row band
  int bid = blockIdx.x;                       // 512 blocks
  int xcd = bid & 7, idx = bid >> 3;          // XCD owns 4 m-tiles, streams 16 n-tiles
  int m0 = (xcd * 4 + (idx & 3)) * 128;
  int n0 = (idx >> 2) * 64;
  int b = m0 >> 10;
  f32x4 accW[2][4] = {}, accV[2][4] = {};
  int arow = tid >> 3;                        // 0..31
  int acol = ((tid & 7) ^ (arow & 7)) * 8;    // pre-swizzled source column
  const u16* agp = A  + (size_t)(m0 + arow) * 2048 + acol;
  const u16* bgp = Bw + (size_t)(n0 + arow) * 2048 + acol;
  u16* adst = Asm + tid * 8;
  u16* bdst = Bsm + tid * 8;
  auto kloop = [&](f32x4 (&acc)[2][4], int kbeg) {
    for (int k0 = kbeg; k0 < kbeg + 1024; k0 += 64) {
      #pragma unroll
      for (int c = 0; c < 4; c++)
        gl_lds16(agp + (size_t)c * 32 * 2048 + k0, adst + c * 2048);
      #pragma unroll
      for (int c = 0; c < 2; c++)
        gl_lds16(bgp + (size_t)c * 32 * 2048 + k0, bdst + c * 2048);
      __syncthreads();
      #pragma unroll
      for (int h2 = 0; h2 < 2; h2++) {
        int sl = ((h2 * 4 + g) ^ (qi & 7)) * 8;
        s16x8 af[2], bf[4];
        #pragma unroll
        for (int i = 0; i < 2; i++)
          af[i] = *(const s16x8*)(Asm + (wave * 32 + i * 16 + qi) * 64 + sl);
        #pragma unroll
        for (int j = 0; j < 4; j++)
          bf[j] = *(const s16x8*)(Bsm + (j * 16 + qi) * 64 + sl);
        __builtin_amdgcn_s_setprio(1);
        #pragma unroll
        for (int i = 0; i < 2; i++)
          #pragma unroll
          for (int j = 0; j < 4; j++)
            acc[i][j] = __builtin_amdgcn_mfma_f32_16x16x32_bf16(af[i], bf[j], acc[i][j], 0, 0, 0);
        __builtin_amdgcn_s_setprio(0);
      }
      __syncthreads();
    }
  };
  kloop(accW, 0);
  kloop(accV, 1024);
  float ns = nst[0];
  #pragma unroll
  for (int i = 0; i < 2; i++) {
    #pragma unroll
    for (int j = 0; j < 4; j++) {
      int n = n0 + j * 16 + qi;
      float bv = bias[n];
      float wd = scl_ou[b * 1024 + n];
      float ud = scl_ou[4096 + b * 1024 + n];
      #pragma unroll
      for (int r = 0; r < 4; r++) {
        int mrow = m0 + wave * 32 + i * 16 + g * 4 + r;
        float v = accW[i][j][r] * wd + accV[i][j][r] * ud + noi[mrow] * ns + bv;
        v = (v >= 0.f) ? v : 0.2f * v;
        v = fminf(fmaxf(v, -256.f), 256.f);
        out[(size_t)mrow * 1024 + n] = v;
      }
    }
  }
}

extern "C" void kernel_launch(void* const* d_in, const int* in_sizes, int n_in,
                              void* d_out, int out_size, void* d_ws, size_t ws_size,
                              hipStream_t stream) {
  const float* x    = (const float*)d_in[0];
  const float* w    = (const float*)d_in[1];
  const float* aw   = (const float*)d_in[2];
  const float* ab   = (const float*)d_in[3];
  const float* qw   = (const float*)d_in[4];
  const float* kw   = (const float*)d_in[5];
  const float* vw   = (const float*)d_in[6];
  const float* wwp  = (const float*)d_in[7];
  const float* uwp  = (const float*)d_in[8];
  const float* bias = (const float*)d_in[9];
  const float* nst  = (const float*)d_in[10];
  const float* noi  = (const float*)d_in[11];
  float* out = (float*)d_out;

  char* ws = (char*)d_ws;
  float* styles  = (float*)ws;  ws += 8192 * 4;           // [4][2048]
  float* scl_qkv = (float*)ws;  ws += 3 * 4096 * 4;       // [3][4][1024]
  float* scl_ou  = (float*)ws;  ws += 2 * 4096 * 4;       // [2][4][1024]
  u16* xn   = (u16*)ws;         ws += (size_t)4194304 * 2; // [4096][1024]
  u16* wbq  = (u16*)ws;         ws += (size_t)3145728 * 2; // [3][1024][1024]
  u16* wcat = (u16*)ws;         ws += (size_t)2097152 * 2; // [1024][2048] = [Ww|Uw]
  u16* qb   = (u16*)ws;         ws += (size_t)4194304 * 2; // [4096][1024]
  u16* kb   = (u16*)ws;         ws += (size_t)4194304 * 2; // [4096][1024]
  u16* vt   = (u16*)ws;         ws += (size_t)4194304 * 2; // [4][1024 hd][1024 s]
  u16* ov   = (u16*)ws;         ws += (size_t)8388608 * 2; // [4096][2048] = [o | v]

  styles_k<<<dim3(512), dim3(256), 0, stream>>>(w, aw, ab, styles);
  dcoef_k<<<dim3(1280), dim3(256), 0, stream>>>(qw, kw, vw, wwp, uwp, styles, scl_qkv, scl_ou);
  lnorm_k<<<dim3(4096), dim3(256), 0, stream>>>(x, styles, xn);
  convall_k<<<dim3(2560), dim3(256), 0, stream>>>(qw, kw, vw, wwp, uwp, wbq, wcat);
  gemm_qkv_k<<<dim3(768), dim3(256), 0, stream>>>(xn, wbq, scl_qkv, qb, kb, ov + 1024, vt);
  attn_k<<<dim3(2048), dim3(256), 0, stream>>>(qb, kb, vt, ov);
  gemm_out_k<<<dim3(512), dim3(256), 0, stream>>>(ov, wcat, scl_ou, noi, nst, bias, out);
}